// Round 3
// baseline (437.314 us; speedup 1.0000x reference)
//
#include <hip/hip_runtime.h>

#define NU 100000
#define NI 50000
#define NN 150000   // NU + NI
#define D  64
#define CAP 47      // bucket capacity per dst; E[max in-degree] ~44 for Poisson(21.3)
#define OVF_MAX 4096

// binning params (256-wide bins: regroup block reads exactly its own records)
#define BINSHIFT 8
#define BINW 256                 // dsts per bin
#define NBINS 586                // ceil(150000/256); 586*256 = 150016
#define BINCAP 5848              // per-bin record cap (mean 5461 + 5 sigma), mult of 8
#define STAGE_CAP 11             // LDS stage slots per bin (11 -> 53.9KB -> 3 blocks/CU)
#define EPT 4                    // edges per thread per batch
#define SPILL_CAP 262144
#define BIN_BLOCKS 768           // 256 CUs x 3 blocks/CU, one round

typedef unsigned int uint;
typedef unsigned short ushort;

// ---------------- helpers ----------------
__device__ __forceinline__ float half_reduce_add(float v) {  // reduce within 32-lane half
    #pragma unroll
    for (int m = 16; m >= 1; m >>= 1) v += __shfl_xor(v, m, 64);
    return v;
}
__device__ __forceinline__ ushort f2bf(float f) {   // round-to-nearest-even
    union { float f; uint i; } c; c.f = f;
    uint r = c.i + 0x7FFF + ((c.i >> 16) & 1);
    return (ushort)(r >> 16);
}
__device__ __forceinline__ float lane_bcast(float v, int l) {
    return __int_as_float(__builtin_amdgcn_readlane(__float_as_int(v), l));
}
// bf14 weight encoding: rounded top-14 bits of f32 (w in [0,1)); decode = 1 AND
__device__ __forceinline__ uint enc14(float w) {
    uint b = __float_as_uint(w) + 0x00020000u;   // round at bit 18
    return b & 0xFFFC0000u;
}
__device__ __forceinline__ float dec14(uint r) {
    return __uint_as_float(r & 0xFFFC0000u);
}
__device__ __forceinline__ void spill_one(int d, uint s, float w,
        uint2* __restrict__ spill, int* __restrict__ spillcnt) {
    int si = atomicAdd(spillcnt, 1);
    if (si < SPILL_CAP) spill[si] = make_uint2(s | enc14(w), (uint)d);
}

// ---------------- pass 1: LDS-staged binning, line-coalesced flushes ----------
// bin record: word0 = src18 | dlocal8<<18 ; word1 = float weight bits
__global__ __launch_bounds__(256) void k_bin(
        const int* __restrict__ src, const int* __restrict__ dst,
        const float* __restrict__ ew, int* __restrict__ bincur,
        uint2* __restrict__ binbuf, uint2* __restrict__ spill,
        int* __restrict__ spillcnt, int E) {
    __shared__ uint2 stage[NBINS][STAGE_CAP];   // 51.6 KB -> 3 blocks/CU
    __shared__ int scnt[NBINS];
    int t = threadIdx.x;
    for (int i = t; i < NBINS; i += 256) scnt[i] = 0;
    __syncthreads();
    const int batch = 256 * EPT;
    for (int base = blockIdx.x * batch; base < E; base += BIN_BLOCKS * batch) {
        int dd[EPT]; uint ss[EPT]; float ww[EPT]; int ok[EPT];
        #pragma unroll
        for (int k = 0; k < EPT; ++k) {
            int e = base + k * 256 + t;
            ok[k] = (e < E);
            if (ok[k]) { dd[k] = dst[e]; ss[k] = (uint)src[e]; ww[k] = ew[e]; }
        }
        #pragma unroll
        for (int k = 0; k < EPT; ++k) {
            if (!ok[k]) continue;
            int bin = dd[k] >> BINSHIFT;
            int slot = atomicAdd(&scnt[bin], 1);
            if (slot < STAGE_CAP) {
                stage[bin][slot] = make_uint2(
                    ss[k] | ((uint)(dd[k] & (BINW - 1)) << 18),
                    (uint)__float_as_int(ww[k]));
            } else {
                spill_one(dd[k], ss[k], ww[k], spill, spillcnt);  // rare
            }
        }
        __syncthreads();
        for (int bin = t; bin < NBINS; bin += 256) {
            int c = scnt[bin]; if (c > STAGE_CAP) c = STAGE_CAP;
            while (c >= 8) {
                int b0 = atomicAdd(&bincur[bin], 8);
                if (b0 + 8 <= BINCAP) {
                    uint4* o4 = (uint4*)(binbuf + (size_t)bin * BINCAP + b0);
                    uint2* s2 = &stage[bin][c - 8];
                    o4[0] = make_uint4(s2[0].x, s2[0].y, s2[1].x, s2[1].y);
                    o4[1] = make_uint4(s2[2].x, s2[2].y, s2[3].x, s2[3].y);
                    o4[2] = make_uint4(s2[4].x, s2[4].y, s2[5].x, s2[5].y);
                    o4[3] = make_uint4(s2[6].x, s2[6].y, s2[7].x, s2[7].y);
                } else {
                    for (int j = 0; j < 8; ++j) {
                        uint2 r = stage[bin][c - 8 + j];
                        spill_one((bin << BINSHIFT) + (int)(r.x >> 18),
                                  r.x & 0x3FFFFu, __int_as_float((int)r.y),
                                  spill, spillcnt);
                    }
                }
                c -= 8;
            }
            scnt[bin] = c;
        }
        __syncthreads();
    }
    // tail drain: contiguous partial appends (<8 per bin per block)
    for (int bin = t; bin < NBINS; bin += 256) {
        int c = scnt[bin]; if (c > STAGE_CAP) c = STAGE_CAP;
        if (c > 0) {
            int b0 = atomicAdd(&bincur[bin], c);
            for (int j = 0; j < c; ++j) {
                uint2 r = stage[bin][j];
                if (b0 + j < BINCAP) binbuf[(size_t)bin * BINCAP + b0 + j] = r;
                else spill_one((bin << BINSHIFT) + (int)(r.x >> 18),
                               r.x & 0x3FFFFu, __int_as_float((int)r.y),
                               spill, spillcnt);
            }
        }
    }
}

// -------- pass 2: regroup + spills + weighted degree + dinv (one block/bin) ---
__global__ __launch_bounds__(256) void k_regroup(
        const int* __restrict__ bincur, const uint2* __restrict__ binbuf,
        const uint2* __restrict__ spill, const int* __restrict__ spillcnt,
        uint* __restrict__ recs, int* __restrict__ cursor,
        float* __restrict__ dinv, int4* __restrict__ ovf,
        int* __restrict__ ovfcnt) {
    __shared__ uint image[256 * CAP];   // 47 KB, layout == recs layout
    __shared__ int cnt[256];
    __shared__ float ovfw[256];
    int t = threadIdx.x;
    int bin = blockIdx.x;
    cnt[t] = 0; ovfw[t] = 0.0f;
    __syncthreads();
    int dbase = bin << BINSHIFT;
    int nrec = bincur[bin]; if (nrec > BINCAP) nrec = BINCAP;
    const uint2* bb = binbuf + (size_t)bin * BINCAP;
    for (int i = t; i < nrec; i += 256) {
        uint2 r = bb[i];
        int dl = (int)(r.x >> 18);          // 8-bit dlocal, top bits zero
        int slot = atomicAdd(&cnt[dl], 1);
        uint s = r.x & 0x3FFFFu;
        float w = __int_as_float((int)r.y);
        if (slot < CAP) image[dl * CAP + slot] = enc14(w) | s;
        else {                                              // rare high-degree
            atomicAdd(&ovfw[dl], w);
            int o = atomicAdd(ovfcnt, 1);
            if (o < OVF_MAX)
                ovf[o] = make_int4(dbase + dl, (int)s, __float_as_int(w), 0);
        }
    }
    // spill entries (normally few); spill words already bf14-encoded
    int ns = spillcnt[0]; if (ns > SPILL_CAP) ns = SPILL_CAP;
    for (int i = t; i < ns; i += 256) {
        uint2 e = spill[i];
        int d = (int)e.y;
        if (d < dbase || d >= dbase + BINW) continue;
        int dl = d - dbase;
        int slot = atomicAdd(&cnt[dl], 1);
        if (slot < CAP) image[dl * CAP + slot] = e.x;
        else {
            float w = dec14(e.x);
            atomicAdd(&ovfw[dl], w);
            int o = atomicAdd(ovfcnt, 1);
            if (o < OVF_MAX) ovf[o] = make_int4(d, (int)(e.x & 0x3FFFFu),
                                                __float_as_int(w), 0);
        }
    }
    __syncthreads();
    int ndl = NN - dbase; if (ndl > 256) ndl = 256;
    if (ndl <= 0) return;
    if (t < ndl) {
        int c = cnt[t];
        cursor[dbase + t] = c;
        if (c > CAP) c = CAP;
        float dg = ovfw[t];
        for (int j = 0; j < c; ++j) dg += dec14(image[t * CAP + j]);
        dinv[dbase + t] = rsqrtf(dg + 1.0f);   // self-loop weight 1 folded in
    }
    int tot = ndl * CAP;
    uint* out = recs + (size_t)dbase * CAP;
    for (int i = t; i < tot; i += 256) out[i] = image[i];  // fully coalesced
}

// ------- layer-1 GEMM: hw2b = bf16((x @ W0) * dinv), x = [U;I] f32 -----------
__global__ __launch_bounds__(256) void k_gemm1(
        const float* __restrict__ U, const float* __restrict__ I,
        const float* __restrict__ W, const float* __restrict__ dinv,
        ushort* __restrict__ out) {
    int lane = threadIdx.x & 63;
    float wreg[64];                         // column `lane` of W0
    #pragma unroll
    for (int k = 0; k < 64; ++k) wreg[k] = W[k * 64 + lane];
    int wpb = blockDim.x >> 6;
    int wid = blockIdx.x * wpb + (threadIdx.x >> 6);
    int tw = gridDim.x * wpb;
    for (int n = wid; n < NN; n += tw) {
        float xv = (n < NU) ? U[(size_t)n * D + lane]
                            : I[(size_t)(n - NU) * D + lane];
        float a0 = 0.f, a1 = 0.f, a2 = 0.f, a3 = 0.f;  // 4 chains (ILP)
        #pragma unroll
        for (int k = 0; k < 64; k += 4) {
            a0 = fmaf(lane_bcast(xv, k + 0), wreg[k + 0], a0);
            a1 = fmaf(lane_bcast(xv, k + 1), wreg[k + 1], a1);
            a2 = fmaf(lane_bcast(xv, k + 2), wreg[k + 2], a2);
            a3 = fmaf(lane_bcast(xv, k + 3), wreg[k + 3], a3);
        }
        out[(size_t)n * D + lane] = f2bf(((a0 + a1) + (a2 + a3)) * dinv[n]);
    }
}

// --- conv accumulate: record broadcast on the DS pipe (ds_bpermute), fully
//     unrolled uniform-guarded software pipeline, 3 chunks (12 gathers) deep --
// hw2p = (const uint*)hw2b: row n = 32 dwords, dword p = bf16 feats (2p, 2p+1).
__device__ __forceinline__ float2 conv_accum2(int n, int lane,
        const uint* __restrict__ hw2p, const int* __restrict__ cursor,
        const uint* __restrict__ recs, const int4* __restrict__ ovf,
        const int* __restrict__ ovfcnt) {
    int cnt = __builtin_amdgcn_readfirstlane(cursor[n]);
    if (cnt > CAP) cnt = CAP;
    uint rv = (lane < cnt) ? recs[(size_t)n * CAP + lane] : 0u;
    const int  vodd4 = (lane >> 5) << 2;          // 0 or 4: even/odd edge half
    const uint lb4   = (uint)(lane & 31) << 2;    // byte offset within row
    // self-loop load issued first (oldest in vmcnt queue, consumed last)
    uint xs = *(const uint*)((const char*)hw2p + (((uint)n << 7) + lb4));
    float ax = 0.f, ay = 0.f;
    int cp = (cnt + 7) & ~7;                      // 0..48, wave-uniform

    // chunk c covers edge pairs P0..P0+3 (edges 2P0..2P0+7).
    // record for this lane's half of pair P sits at record index 2P+odd.
#define CA_DECL(c) uint x##c##0, x##c##1, x##c##2, x##c##3, \
                        w##c##0, w##c##1, w##c##2, w##c##3;
#define CA_GET(c, i, P) { \
    uint r = (uint)__builtin_amdgcn_ds_bpermute(vodd4 + 8 * (P), (int)rv); \
    w##c##i = r & 0xFFFC0000u; \
    x##c##i = *(const uint*)((const char*)hw2p + \
                             (((r & 0x3FFFFu) << 7) + lb4)); }
#define CA_ISSUE(c, P0) { CA_GET(c, 0, (P0)+0) CA_GET(c, 1, (P0)+1) \
                          CA_GET(c, 2, (P0)+2) CA_GET(c, 3, (P0)+3) }
#define CA_FMA1(c, i) { \
    ax = fmaf(__uint_as_float(w##c##i), __uint_as_float(x##c##i << 16), ax); \
    ay = fmaf(__uint_as_float(w##c##i), \
              __uint_as_float(x##c##i & 0xFFFF0000u), ay); }
#define CA_FMA(c) { CA_FMA1(c,0) CA_FMA1(c,1) CA_FMA1(c,2) CA_FMA1(c,3) }

    CA_DECL(A) CA_DECL(B) CA_DECL(G)
    if (cp > 0)  CA_ISSUE(A, 0)        // 3 chunks pre-issued: 12 gathers deep
    if (cp > 8)  CA_ISSUE(B, 4)
    if (cp > 16) CA_ISSUE(G, 8)
    if (cp > 0)  CA_FMA(A)
    if (cp > 24) CA_ISSUE(A, 12)
    if (cp > 8)  CA_FMA(B)
    if (cp > 32) CA_ISSUE(B, 16)
    if (cp > 16) CA_FMA(G)
    if (cp > 40) CA_ISSUE(G, 20)
    if (cp > 24) CA_FMA(A)
    if (cp > 32) CA_FMA(B)
    if (cp > 40) CA_FMA(G)
#undef CA_FMA
#undef CA_FMA1
#undef CA_ISSUE
#undef CA_GET
#undef CA_DECL

    // combine even/odd halves
    ax += __shfl_xor(ax, 32, 64);
    ay += __shfl_xor(ay, 32, 64);
    // self-loop term
    ax += __uint_as_float(xs << 16);
    ay += __uint_as_float(xs & 0xFFFF0000u);
    // overflow list (normally empty)
    int novf = __builtin_amdgcn_readfirstlane(ovfcnt[0]);
    if (novf > 0) {
        if (novf > OVF_MAX) novf = OVF_MAX;
        for (int j = 0; j < novf; ++j) {
            int4 e = ovf[j];
            if (e.x == n) {
                float w = __int_as_float(e.z);
                uint x = hw2p[(size_t)e.y * 32 + (lane & 31)];
                ax = fmaf(w, __int_as_float((int)(x << 16)), ax);
                ay = fmaf(w, __int_as_float((int)(x & 0xFFFF0000u)), ay);
            }
        }
    }
    return make_float2(ax, ay);
}

// bias + LN + ReLU on pair layout; returns (y0,y1) for feats (2p, 2p+1)
__device__ __forceinline__ float2 ln_relu2(float2 a, float di, int p,
        const float* __restrict__ b, const float* __restrict__ g,
        const float* __restrict__ be) {
    float2 bb = ((const float2*)b)[p];
    float v0 = fmaf(a.x, di, bb.x);
    float v1 = fmaf(a.y, di, bb.y);
    float m = half_reduce_add(v0 + v1) * (1.0f / 64.0f);
    float d0 = v0 - m, d1 = v1 - m;
    float var = half_reduce_add(d0 * d0 + d1 * d1) * (1.0f / 64.0f);
    float rs = rsqrtf(var + 1e-5f);
    float2 gg = ((const float2*)g)[p];
    float2 ee = ((const float2*)be)[p];
    return make_float2(fmaxf(fmaf(d0 * rs, gg.x, ee.x), 0.0f),
                       fmaxf(fmaf(d1 * rs, gg.y, ee.y), 0.0f));
}

// --- layer-1 conv (all nodes) + bias + LN + ReLU + residual; h1 out in bf16 --
__global__ __launch_bounds__(256) void k_conv1(
        const uint* __restrict__ hw2p, const int* __restrict__ cursor,
        const uint* __restrict__ recs, const int4* __restrict__ ovf,
        const int* __restrict__ ovfcnt, const float* __restrict__ dinv,
        const float* __restrict__ b, const float* __restrict__ g,
        const float* __restrict__ be, const float* __restrict__ U,
        const float* __restrict__ I, uint* __restrict__ out1) {
    int lane = threadIdx.x & 63;
    int n = __builtin_amdgcn_readfirstlane(blockIdx.x * 4 + (threadIdx.x >> 6));
    if (n >= NN) return;
    float2 a = conv_accum2(n, lane, hw2p, cursor, recs, ovf, ovfcnt);
    int p = lane & 31;
    float2 y = ln_relu2(a, dinv[n], p, b, g, be);
    const float* R = (n < NU) ? (U + (size_t)n * D) : (I + (size_t)(n - NU) * D);
    float2 rr = ((const float2*)R)[p];
    if (lane < 32) {
        out1[(size_t)n * 32 + p] =
            (uint)f2bf(y.x + rr.x) | ((uint)f2bf(y.y + rr.y) << 16);
    }
}

// ------- layer-2 GEMM: hw2b = bf16((h1 @ W1) * dinv), h1 read as bf16 --------
__global__ __launch_bounds__(256) void k_gemm2(
        const ushort* __restrict__ hb, const float* __restrict__ W,
        const float* __restrict__ dinv, ushort* __restrict__ out) {
    int lane = threadIdx.x & 63;
    float wreg[64];                         // column `lane` of W1
    #pragma unroll
    for (int k = 0; k < 64; ++k) wreg[k] = W[k * 64 + lane];
    int wpb = blockDim.x >> 6;
    int wid = blockIdx.x * wpb + (threadIdx.x >> 6);
    int tw = gridDim.x * wpb;
    for (int n = wid; n < NN; n += tw) {
        float xv = __uint_as_float((uint)hb[(size_t)n * D + lane] << 16);
        float a0 = 0.f, a1 = 0.f, a2 = 0.f, a3 = 0.f;
        #pragma unroll
        for (int k = 0; k < 64; k += 4) {
            a0 = fmaf(lane_bcast(xv, k + 0), wreg[k + 0], a0);
            a1 = fmaf(lane_bcast(xv, k + 1), wreg[k + 1], a1);
            a2 = fmaf(lane_bcast(xv, k + 2), wreg[k + 2], a2);
            a3 = fmaf(lane_bcast(xv, k + 3), wreg[k + 3], a3);
        }
        out[(size_t)n * D + lane] = f2bf(((a0 + a1) + (a2 + a3)) * dinv[n]);
    }
}

// ------- FUSED layer-2 conv (sampled) + projection + scoring ------------------
__global__ __launch_bounds__(256) void k_conv2score(
        const uint* __restrict__ hw2p, const int* __restrict__ cursor,
        const uint* __restrict__ recs, const int4* __restrict__ ovf,
        const int* __restrict__ ovfcnt, const float* __restrict__ dinv,
        const float* __restrict__ b, const float* __restrict__ g,
        const float* __restrict__ be, const int* __restrict__ users,
        const int* __restrict__ items, const uint* __restrict__ h1b,
        const float* __restrict__ Wp, const float* __restrict__ bp,
        const float* __restrict__ bu, const float* __restrict__ bi,
        const float* __restrict__ mu, float* __restrict__ out, int B) {
    int lane = threadIdx.x & 63;
    float wreg[64];                         // column `lane` of Wp
    #pragma unroll
    for (int k = 0; k < 64; ++k) wreg[k] = Wp[k * 64 + lane];
    float bpl = bp[lane];
    int q = lane & 31;
    int wpb = blockDim.x >> 6;
    int wid = blockIdx.x * wpb + (threadIdx.x >> 6);
    int tw = gridDim.x * wpb;
    for (int p = wid; p < B; p += tw) {
        int un = users[p];
        int in = NU + items[p];
        // --- user node conv + LN + residual (bf16 h1 residual)
        int nu = __builtin_amdgcn_readfirstlane(un);
        float2 au = conv_accum2(nu, lane, hw2p, cursor, recs, ovf, ovfcnt);
        float2 yu = ln_relu2(au, dinv[nu], q, b, g, be);
        uint xu = h1b[(size_t)nu * 32 + q];
        float2 hu = make_float2(yu.x + __uint_as_float(xu << 16),
                                yu.y + __uint_as_float(xu & 0xFFFF0000u));
        // --- item node
        int ni = __builtin_amdgcn_readfirstlane(in);
        float2 ai = conv_accum2(ni, lane, hw2p, cursor, recs, ovf, ovfcnt);
        float2 yi = ln_relu2(ai, dinv[ni], q, b, g, be);
        uint xi = h1b[(size_t)ni * 32 + q];
        float2 hi = make_float2(yi.x + __uint_as_float(xi << 16),
                                yi.y + __uint_as_float(xi & 0xFFFF0000u));
        // --- projection (feat 2j from .x, 2j+1 from .y) + dot
        float pu = bpl, pi = bpl;
        #pragma unroll
        for (int j = 0; j < 32; ++j) {
            pu = fmaf(lane_bcast(hu.x, j), wreg[2 * j], pu);
            pu = fmaf(lane_bcast(hu.y, j), wreg[2 * j + 1], pu);
            pi = fmaf(lane_bcast(hi.x, j), wreg[2 * j], pi);
            pi = fmaf(lane_bcast(hi.y, j), wreg[2 * j + 1], pi);
        }
        float t = pu * pi;
        #pragma unroll
        for (int m = 32; m >= 1; m >>= 1) t += __shfl_xor(t, m, 64);
        if (lane == 0) {
            t += bu[un] + bi[in - NU] + mu[0];
            out[p] = fminf(fmaxf(t, 1.0f), 5.0f);
        }
    }
}

extern "C" void kernel_launch(void* const* d_in, const int* in_sizes, int n_in,
                              void* d_out, int out_size, void* d_ws, size_t ws_size,
                              hipStream_t stream) {
    const int*   users = (const int*)d_in[0];
    const int*   items = (const int*)d_in[1];
    const int*   ei2   = (const int*)d_in[2];
    const float* ew    = (const float*)d_in[3];
    const float* U     = (const float*)d_in[4];
    const float* I     = (const float*)d_in[5];
    const float* W0    = (const float*)d_in[6];
    const float* b0    = (const float*)d_in[7];
    const float* g0    = (const float*)d_in[8];
    const float* be0   = (const float*)d_in[9];
    const float* W1    = (const float*)d_in[10];
    const float* b1    = (const float*)d_in[11];
    const float* g1    = (const float*)d_in[12];
    const float* be1   = (const float*)d_in[13];
    const float* Wp    = (const float*)d_in[14];
    const float* bp    = (const float*)d_in[15];
    const float* bu    = (const float*)d_in[16];
    const float* bi    = (const float*)d_in[17];
    const float* mu    = (const float*)d_in[18];

    int B = in_sizes[0];
    int E = in_sizes[2] / 2;
    const int* srcp = ei2;
    const int* dstp = ei2 + E;

    // workspace carve-up (256B aligned)
    char* p = (char*)d_ws;
    auto alloc = [&](size_t bytes) -> char* {
        char* r = p;
        p += (bytes + 255) & ~(size_t)255;
        return r;
    };
    int*    cbuf    = (int*)  alloc((size_t)(NBINS + 8) * 4);  // bincur|spillcnt|ovfcnt
    int*    bincur  = cbuf;
    int*    spillcnt= cbuf + NBINS;
    int*    ovfcnt  = cbuf + NBINS + 1;
    int*    cursor  = (int*)  alloc((size_t)NN * 4);
    float*  dinv    = (float*)alloc((size_t)NN * 4);
    int4*   ovf     = (int4*) alloc((size_t)OVF_MAX * 16);
    uint2*  spill   = (uint2*)alloc((size_t)SPILL_CAP * 8);      // 2.1 MB
    uint2*  binbuf  = (uint2*)alloc((size_t)NBINS * BINCAP * 8); // 27.4 MB
    uint*   recs    = (uint*) alloc((size_t)NN * CAP * 4);       // 28.2 MB
    ushort* hw2b    = (ushort*)alloc((size_t)NN * D * 2);        // 19.2 MB
    uint*   h1b     = (uint*) alloc((size_t)NN * 32 * 4);        // 19.2 MB (bf16)
    const uint* hw2p = (const uint*)hw2b;

    hipMemsetAsync(cbuf, 0, (size_t)(NBINS + 8) * 4, stream);

    int gW = (NN + 3) / 4;          // one wave per node, 4 waves/block

    // CSR build: bin -> regroup(+spill+deg+dinv)
    k_bin<<<BIN_BLOCKS, 256, 0, stream>>>(srcp, dstp, ew, bincur, binbuf,
                                          spill, spillcnt, E);
    k_regroup<<<NBINS, 256, 0, stream>>>(bincur, binbuf, spill, spillcnt,
                                         recs, cursor, dinv, ovf, ovfcnt);

    // layer 1 (all nodes)
    k_gemm1<<<2048, 256, 0, stream>>>(U, I, W0, dinv, hw2b);
    k_conv1<<<gW, 256, 0, stream>>>(hw2p, cursor, recs, ovf, ovfcnt, dinv,
                                    b0, g0, be0, U, I, h1b);
    // layer 2: gemm all nodes (bf16 in), then fused sampled conv+proj+score
    k_gemm2<<<2048, 256, 0, stream>>>((const ushort*)h1b, W1, dinv, hw2b);
    k_conv2score<<<1024, 256, 0, stream>>>(hw2p, cursor, recs, ovf, ovfcnt, dinv,
                                           b1, g1, be1, users, items, h1b,
                                           Wp, bp, bu, bi, mu,
                                           (float*)d_out, B);
}

// Round 4
// 431.084 us; speedup vs baseline: 1.0145x; 1.0145x over previous
//
#include <hip/hip_runtime.h>

#define NU 100000
#define NI 50000
#define NN 150000   // NU + NI
#define D  64
#define CAP 47      // bucket capacity per dst; E[max in-degree] ~44 for Poisson(21.3)
#define OVF_MAX 4096

// binning params (256-wide bins: regroup block reads exactly its own records)
#define BINSHIFT 8
#define BINW 256                 // dsts per bin
#define NBINS 586                // ceil(150000/256); 586*256 = 150016
#define BINCAP 5848              // per-bin record cap, mult of 8
#define STAGE_CAP 11             // LDS stage slots per bin (53.9KB -> 3 blocks/CU)
#define EPT 4                    // edges per thread per batch
#define SPILL_CAP 262144
#define BIN_BLOCKS 768           // 256 CUs x 3 blocks/CU, one round

typedef unsigned int uint;
typedef unsigned short ushort;
typedef unsigned char uchar;

// ---------------- helpers ----------------
__device__ __forceinline__ float half_reduce_add(float v) {  // reduce within 32-lane half
    #pragma unroll
    for (int m = 16; m >= 1; m >>= 1) v += __shfl_xor(v, m, 64);
    return v;
}
__device__ __forceinline__ ushort f2bf(float f) {   // round-to-nearest-even
    union { float f; uint i; } c; c.f = f;
    uint r = c.i + 0x7FFF + ((c.i >> 16) & 1);
    return (ushort)(r >> 16);
}
__device__ __forceinline__ float lane_bcast(float v, int l) {
    return __int_as_float(__builtin_amdgcn_readlane(__float_as_int(v), l));
}
// bf14 weight encoding: rounded top-14 bits of f32 (w in [0,1)); decode = 1 AND
__device__ __forceinline__ uint enc14(float w) {
    uint b = __float_as_uint(w) + 0x00020000u;   // round at bit 18
    return b & 0xFFFC0000u;
}
__device__ __forceinline__ float dec14(uint r) {
    return __uint_as_float(r & 0xFFFC0000u);
}
__device__ __forceinline__ void spill_one(int d, uint s, float w,
        uint2* __restrict__ spill, int* __restrict__ spillcnt) {
    int si = atomicAdd(spillcnt, 1);
    if (si < SPILL_CAP) spill[si] = make_uint2(s | enc14(w), (uint)d);
}

// ---------------- pass 1: LDS-staged binning, line-coalesced flushes ----------
// bin record: word0 = src18 | dlocal8<<18 ; word1 = float weight bits
// Residuals (<8 per bin) are NOT scalar-scattered to binbuf (R3's 88us
// bottleneck: ~1.6M scalar stores + 450K contended atomics). Instead each
// block dumps stage slots 0..7 of every bin linearly (coalesced, no atomics)
// into tail[block] + a count table; k_regroup gathers them per-bin.
__global__ __launch_bounds__(256) void k_bin(
        const int* __restrict__ src, const int* __restrict__ dst,
        const float* __restrict__ ew, int* __restrict__ bincur,
        uint2* __restrict__ binbuf, uint2* __restrict__ spill,
        int* __restrict__ spillcnt, uint2* __restrict__ tail,
        uchar* __restrict__ cnt8, int E) {
    __shared__ uint2 stage[NBINS][STAGE_CAP];   // 51.6 KB -> 3 blocks/CU
    __shared__ int scnt[NBINS];
    int t = threadIdx.x;
    for (int i = t; i < NBINS; i += 256) scnt[i] = 0;
    __syncthreads();
    const int batch = 256 * EPT;
    for (int base = blockIdx.x * batch; base < E; base += BIN_BLOCKS * batch) {
        int dd[EPT]; uint ss[EPT]; float ww[EPT]; int ok[EPT];
        #pragma unroll
        for (int k = 0; k < EPT; ++k) {
            int e = base + k * 256 + t;
            ok[k] = (e < E);
            if (ok[k]) { dd[k] = dst[e]; ss[k] = (uint)src[e]; ww[k] = ew[e]; }
        }
        #pragma unroll
        for (int k = 0; k < EPT; ++k) {
            if (!ok[k]) continue;
            int bin = dd[k] >> BINSHIFT;
            int slot = atomicAdd(&scnt[bin], 1);
            if (slot < STAGE_CAP) {
                stage[bin][slot] = make_uint2(
                    ss[k] | ((uint)(dd[k] & (BINW - 1)) << 18),
                    (uint)__float_as_int(ww[k]));
            } else {
                spill_one(dd[k], ss[k], ww[k], spill, spillcnt);  // rare
            }
        }
        __syncthreads();
        for (int bin = t; bin < NBINS; bin += 256) {
            int c = scnt[bin]; if (c > STAGE_CAP) c = STAGE_CAP;
            while (c >= 8) {                // takes TOP 8, leaves bottom c-8
                int b0 = atomicAdd(&bincur[bin], 8);
                if (b0 + 8 <= BINCAP) {
                    uint4* o4 = (uint4*)(binbuf + (size_t)bin * BINCAP + b0);
                    uint2* s2 = &stage[bin][c - 8];
                    o4[0] = make_uint4(s2[0].x, s2[0].y, s2[1].x, s2[1].y);
                    o4[1] = make_uint4(s2[2].x, s2[2].y, s2[3].x, s2[3].y);
                    o4[2] = make_uint4(s2[4].x, s2[4].y, s2[5].x, s2[5].y);
                    o4[3] = make_uint4(s2[6].x, s2[6].y, s2[7].x, s2[7].y);
                } else {
                    for (int j = 0; j < 8; ++j) {
                        uint2 r = stage[bin][c - 8 + j];
                        spill_one((bin << BINSHIFT) + (int)(r.x >> 18),
                                  r.x & 0x3FFFFu, __int_as_float((int)r.y),
                                  spill, spillcnt);
                    }
                }
                c -= 8;
            }
            scnt[bin] = c;
        }
        __syncthreads();
    }
    // final residuals: c <= 7 per bin, in stage slots [0, c). Coalesced dump.
    uchar* cb = cnt8 + (size_t)blockIdx.x * NBINS;
    for (int i = t; i < NBINS; i += 256) cb[i] = (uchar)scnt[i];
    uint2* tb = tail + (size_t)blockIdx.x * (NBINS * 8);
    for (int i = t; i < NBINS * 8; i += 256) tb[i] = stage[i >> 3][i & 7];
}

// -------- pass 2: regroup + tails + spills + weighted degree + dinv -----------
__global__ __launch_bounds__(256) void k_regroup(
        const int* __restrict__ bincur, const uint2* __restrict__ binbuf,
        const uint2* __restrict__ spill, const int* __restrict__ spillcnt,
        const uint2* __restrict__ tail, const uchar* __restrict__ cnt8,
        uint* __restrict__ recs, int* __restrict__ cursor,
        float* __restrict__ dinv, int4* __restrict__ ovf,
        int* __restrict__ ovfcnt) {
    __shared__ uint image[256 * CAP];   // 47 KB, layout == recs layout
    __shared__ int cnt[256];
    __shared__ float ovfw[256];
    int t = threadIdx.x;
    int bin = blockIdx.x;
    cnt[t] = 0; ovfw[t] = 0.0f;
    __syncthreads();
    int dbase = bin << BINSHIFT;
    int nrec = bincur[bin]; if (nrec > BINCAP) nrec = BINCAP;
    const uint2* bb = binbuf + (size_t)bin * BINCAP;
    for (int i = t; i < nrec; i += 256) {
        uint2 r = bb[i];
        int dl = (int)(r.x >> 18);          // 8-bit dlocal, top bits zero
        int slot = atomicAdd(&cnt[dl], 1);
        uint s = r.x & 0x3FFFFu;
        float w = __int_as_float((int)r.y);
        if (slot < CAP) image[dl * CAP + slot] = enc14(w) | s;
        else {                                              // rare high-degree
            atomicAdd(&ovfw[dl], w);
            int o = atomicAdd(ovfcnt, 1);
            if (o < OVF_MAX)
                ovf[o] = make_int4(dbase + dl, (int)s, __float_as_int(w), 0);
        }
    }
    // per-block residual tails for this bin (~half of all records)
    for (int g = t; g < BIN_BLOCKS; g += 256) {
        int c = cnt8[(size_t)g * NBINS + bin];
        const uint2* tb = tail + ((size_t)g * NBINS + bin) * 8;
        for (int j = 0; j < c; ++j) {
            uint2 r = tb[j];
            int dl = (int)(r.x >> 18);
            int slot = atomicAdd(&cnt[dl], 1);
            uint s = r.x & 0x3FFFFu;
            float w = __int_as_float((int)r.y);
            if (slot < CAP) image[dl * CAP + slot] = enc14(w) | s;
            else {
                atomicAdd(&ovfw[dl], w);
                int o = atomicAdd(ovfcnt, 1);
                if (o < OVF_MAX)
                    ovf[o] = make_int4(dbase + dl, (int)s, __float_as_int(w), 0);
            }
        }
    }
    // spill entries (rare); spill words already bf14-encoded
    int ns = spillcnt[0]; if (ns > SPILL_CAP) ns = SPILL_CAP;
    for (int i = t; i < ns; i += 256) {
        uint2 e = spill[i];
        int d = (int)e.y;
        if (d < dbase || d >= dbase + BINW) continue;
        int dl = d - dbase;
        int slot = atomicAdd(&cnt[dl], 1);
        if (slot < CAP) image[dl * CAP + slot] = e.x;
        else {
            float w = dec14(e.x);
            atomicAdd(&ovfw[dl], w);
            int o = atomicAdd(ovfcnt, 1);
            if (o < OVF_MAX) ovf[o] = make_int4(d, (int)(e.x & 0x3FFFFu),
                                                __float_as_int(w), 0);
        }
    }
    __syncthreads();
    int ndl = NN - dbase; if (ndl > 256) ndl = 256;
    if (ndl <= 0) return;
    if (t < ndl) {
        int c = cnt[t];
        cursor[dbase + t] = c;
        if (c > CAP) c = CAP;
        float dg = ovfw[t];
        for (int j = 0; j < c; ++j) dg += dec14(image[t * CAP + j]);
        dinv[dbase + t] = rsqrtf(dg + 1.0f);   // self-loop weight 1 folded in
    }
    int tot = ndl * CAP;
    uint* out = recs + (size_t)dbase * CAP;
    for (int i = t; i < tot; i += 256) out[i] = image[i];  // fully coalesced
}

// ------- layer-1 GEMM: hw2b = bf16((x @ W0) * dinv), x = [U;I] f32 -----------
__global__ __launch_bounds__(256) void k_gemm1(
        const float* __restrict__ U, const float* __restrict__ I,
        const float* __restrict__ W, const float* __restrict__ dinv,
        ushort* __restrict__ out) {
    int lane = threadIdx.x & 63;
    float wreg[64];                         // column `lane` of W0
    #pragma unroll
    for (int k = 0; k < 64; ++k) wreg[k] = W[k * 64 + lane];
    int wpb = blockDim.x >> 6;
    int wid = blockIdx.x * wpb + (threadIdx.x >> 6);
    int tw = gridDim.x * wpb;
    for (int n = wid; n < NN; n += tw) {
        float xv = (n < NU) ? U[(size_t)n * D + lane]
                            : I[(size_t)(n - NU) * D + lane];
        float a0 = 0.f, a1 = 0.f, a2 = 0.f, a3 = 0.f;  // 4 chains (ILP)
        #pragma unroll
        for (int k = 0; k < 64; k += 4) {
            a0 = fmaf(lane_bcast(xv, k + 0), wreg[k + 0], a0);
            a1 = fmaf(lane_bcast(xv, k + 1), wreg[k + 1], a1);
            a2 = fmaf(lane_bcast(xv, k + 2), wreg[k + 2], a2);
            a3 = fmaf(lane_bcast(xv, k + 3), wreg[k + 3], a3);
        }
        out[(size_t)n * D + lane] = f2bf(((a0 + a1) + (a2 + a3)) * dinv[n]);
    }
}

// --- conv accumulate: record broadcast on the DS pipe (ds_bpermute), fully
//     unrolled uniform-guarded software pipeline, 3 chunks (12 gathers) deep --
// hw2p = (const uint*)hw2b: row n = 32 dwords, dword p = bf16 feats (2p, 2p+1).
__device__ __forceinline__ float2 conv_accum2(int n, int lane,
        const uint* __restrict__ hw2p, const int* __restrict__ cursor,
        const uint* __restrict__ recs, const int4* __restrict__ ovf,
        const int* __restrict__ ovfcnt) {
    int cnt = __builtin_amdgcn_readfirstlane(cursor[n]);
    if (cnt > CAP) cnt = CAP;
    uint rv = (lane < cnt) ? recs[(size_t)n * CAP + lane] : 0u;
    const int  vodd4 = (lane >> 5) << 2;          // 0 or 4: even/odd edge half
    const uint lb4   = (uint)(lane & 31) << 2;    // byte offset within row
    // self-loop load issued first (oldest in vmcnt queue, consumed last)
    uint xs = *(const uint*)((const char*)hw2p + (((uint)n << 7) + lb4));
    float ax = 0.f, ay = 0.f;
    int cp = (cnt + 7) & ~7;                      // 0..48, wave-uniform

    // chunk c covers edge pairs P0..P0+3 (edges 2P0..2P0+7).
    // record for this lane's half of pair P sits at record index 2P+odd.
#define CA_DECL(c) uint x##c##0, x##c##1, x##c##2, x##c##3, \
                        w##c##0, w##c##1, w##c##2, w##c##3;
#define CA_GET(c, i, P) { \
    uint r = (uint)__builtin_amdgcn_ds_bpermute(vodd4 + 8 * (P), (int)rv); \
    w##c##i = r & 0xFFFC0000u; \
    x##c##i = *(const uint*)((const char*)hw2p + \
                             (((r & 0x3FFFFu) << 7) + lb4)); }
#define CA_ISSUE(c, P0) { CA_GET(c, 0, (P0)+0) CA_GET(c, 1, (P0)+1) \
                          CA_GET(c, 2, (P0)+2) CA_GET(c, 3, (P0)+3) }
#define CA_FMA1(c, i) { \
    ax = fmaf(__uint_as_float(w##c##i), __uint_as_float(x##c##i << 16), ax); \
    ay = fmaf(__uint_as_float(w##c##i), \
              __uint_as_float(x##c##i & 0xFFFF0000u), ay); }
#define CA_FMA(c) { CA_FMA1(c,0) CA_FMA1(c,1) CA_FMA1(c,2) CA_FMA1(c,3) }

    CA_DECL(A) CA_DECL(B) CA_DECL(G)
    if (cp > 0)  CA_ISSUE(A, 0)        // 3 chunks pre-issued: 12 gathers deep
    if (cp > 8)  CA_ISSUE(B, 4)
    if (cp > 16) CA_ISSUE(G, 8)
    if (cp > 0)  CA_FMA(A)
    if (cp > 24) CA_ISSUE(A, 12)
    if (cp > 8)  CA_FMA(B)
    if (cp > 32) CA_ISSUE(B, 16)
    if (cp > 16) CA_FMA(G)
    if (cp > 40) CA_ISSUE(G, 20)
    if (cp > 24) CA_FMA(A)
    if (cp > 32) CA_FMA(B)
    if (cp > 40) CA_FMA(G)
#undef CA_FMA
#undef CA_FMA1
#undef CA_ISSUE
#undef CA_GET
#undef CA_DECL

    // combine even/odd halves
    ax += __shfl_xor(ax, 32, 64);
    ay += __shfl_xor(ay, 32, 64);
    // self-loop term
    ax += __uint_as_float(xs << 16);
    ay += __uint_as_float(xs & 0xFFFF0000u);
    // overflow list (normally empty)
    int novf = __builtin_amdgcn_readfirstlane(ovfcnt[0]);
    if (novf > 0) {
        if (novf > OVF_MAX) novf = OVF_MAX;
        for (int j = 0; j < novf; ++j) {
            int4 e = ovf[j];
            if (e.x == n) {
                float w = __int_as_float(e.z);
                uint x = hw2p[(size_t)e.y * 32 + (lane & 31)];
                ax = fmaf(w, __int_as_float((int)(x << 16)), ax);
                ay = fmaf(w, __int_as_float((int)(x & 0xFFFF0000u)), ay);
            }
        }
    }
    return make_float2(ax, ay);
}

// bias + LN + ReLU on pair layout; returns (y0,y1) for feats (2p, 2p+1)
__device__ __forceinline__ float2 ln_relu2(float2 a, float di, int p,
        const float* __restrict__ b, const float* __restrict__ g,
        const float* __restrict__ be) {
    float2 bb = ((const float2*)b)[p];
    float v0 = fmaf(a.x, di, bb.x);
    float v1 = fmaf(a.y, di, bb.y);
    float m = half_reduce_add(v0 + v1) * (1.0f / 64.0f);
    float d0 = v0 - m, d1 = v1 - m;
    float var = half_reduce_add(d0 * d0 + d1 * d1) * (1.0f / 64.0f);
    float rs = rsqrtf(var + 1e-5f);
    float2 gg = ((const float2*)g)[p];
    float2 ee = ((const float2*)be)[p];
    return make_float2(fmaxf(fmaf(d0 * rs, gg.x, ee.x), 0.0f),
                       fmaxf(fmaf(d1 * rs, gg.y, ee.y), 0.0f));
}

// --- layer-1 conv (all nodes) + bias + LN + ReLU + residual; h1 out in bf16 --
__global__ __launch_bounds__(256) void k_conv1(
        const uint* __restrict__ hw2p, const int* __restrict__ cursor,
        const uint* __restrict__ recs, const int4* __restrict__ ovf,
        const int* __restrict__ ovfcnt, const float* __restrict__ dinv,
        const float* __restrict__ b, const float* __restrict__ g,
        const float* __restrict__ be, const float* __restrict__ U,
        const float* __restrict__ I, uint* __restrict__ out1) {
    int lane = threadIdx.x & 63;
    int n = __builtin_amdgcn_readfirstlane(blockIdx.x * 4 + (threadIdx.x >> 6));
    if (n >= NN) return;
    float2 a = conv_accum2(n, lane, hw2p, cursor, recs, ovf, ovfcnt);
    int p = lane & 31;
    float2 y = ln_relu2(a, dinv[n], p, b, g, be);
    const float* R = (n < NU) ? (U + (size_t)n * D) : (I + (size_t)(n - NU) * D);
    float2 rr = ((const float2*)R)[p];
    if (lane < 32) {
        out1[(size_t)n * 32 + p] =
            (uint)f2bf(y.x + rr.x) | ((uint)f2bf(y.y + rr.y) << 16);
    }
}

// ------- layer-2 GEMM: hw2b = bf16((h1 @ W1) * dinv), h1 read as bf16 --------
__global__ __launch_bounds__(256) void k_gemm2(
        const ushort* __restrict__ hb, const float* __restrict__ W,
        const float* __restrict__ dinv, ushort* __restrict__ out) {
    int lane = threadIdx.x & 63;
    float wreg[64];                         // column `lane` of W1
    #pragma unroll
    for (int k = 0; k < 64; ++k) wreg[k] = W[k * 64 + lane];
    int wpb = blockDim.x >> 6;
    int wid = blockIdx.x * wpb + (threadIdx.x >> 6);
    int tw = gridDim.x * wpb;
    for (int n = wid; n < NN; n += tw) {
        float xv = __uint_as_float((uint)hb[(size_t)n * D + lane] << 16);
        float a0 = 0.f, a1 = 0.f, a2 = 0.f, a3 = 0.f;
        #pragma unroll
        for (int k = 0; k < 64; k += 4) {
            a0 = fmaf(lane_bcast(xv, k + 0), wreg[k + 0], a0);
            a1 = fmaf(lane_bcast(xv, k + 1), wreg[k + 1], a1);
            a2 = fmaf(lane_bcast(xv, k + 2), wreg[k + 2], a2);
            a3 = fmaf(lane_bcast(xv, k + 3), wreg[k + 3], a3);
        }
        out[(size_t)n * D + lane] = f2bf(((a0 + a1) + (a2 + a3)) * dinv[n]);
    }
}

// ------- FUSED layer-2 conv (sampled) + projection + scoring ------------------
__global__ __launch_bounds__(256) void k_conv2score(
        const uint* __restrict__ hw2p, const int* __restrict__ cursor,
        const uint* __restrict__ recs, const int4* __restrict__ ovf,
        const int* __restrict__ ovfcnt, const float* __restrict__ dinv,
        const float* __restrict__ b, const float* __restrict__ g,
        const float* __restrict__ be, const int* __restrict__ users,
        const int* __restrict__ items, const uint* __restrict__ h1b,
        const float* __restrict__ Wp, const float* __restrict__ bp,
        const float* __restrict__ bu, const float* __restrict__ bi,
        const float* __restrict__ mu, float* __restrict__ out, int B) {
    int lane = threadIdx.x & 63;
    float wreg[64];                         // column `lane` of Wp
    #pragma unroll
    for (int k = 0; k < 64; ++k) wreg[k] = Wp[k * 64 + lane];
    float bpl = bp[lane];
    int q = lane & 31;
    int wpb = blockDim.x >> 6;
    int wid = blockIdx.x * wpb + (threadIdx.x >> 6);
    int tw = gridDim.x * wpb;
    for (int p = wid; p < B; p += tw) {
        int un = users[p];
        int in = NU + items[p];
        // --- user node conv + LN + residual (bf16 h1 residual)
        int nu = __builtin_amdgcn_readfirstlane(un);
        float2 au = conv_accum2(nu, lane, hw2p, cursor, recs, ovf, ovfcnt);
        float2 yu = ln_relu2(au, dinv[nu], q, b, g, be);
        uint xu = h1b[(size_t)nu * 32 + q];
        float2 hu = make_float2(yu.x + __uint_as_float(xu << 16),
                                yu.y + __uint_as_float(xu & 0xFFFF0000u));
        // --- item node
        int ni = __builtin_amdgcn_readfirstlane(in);
        float2 ai = conv_accum2(ni, lane, hw2p, cursor, recs, ovf, ovfcnt);
        float2 yi = ln_relu2(ai, dinv[ni], q, b, g, be);
        uint xi = h1b[(size_t)ni * 32 + q];
        float2 hi = make_float2(yi.x + __uint_as_float(xi << 16),
                                yi.y + __uint_as_float(xi & 0xFFFF0000u));
        // --- projection (feat 2j from .x, 2j+1 from .y) + dot
        float pu = bpl, pi = bpl;
        #pragma unroll
        for (int j = 0; j < 32; ++j) {
            pu = fmaf(lane_bcast(hu.x, j), wreg[2 * j], pu);
            pu = fmaf(lane_bcast(hu.y, j), wreg[2 * j + 1], pu);
            pi = fmaf(lane_bcast(hi.x, j), wreg[2 * j], pi);
            pi = fmaf(lane_bcast(hi.y, j), wreg[2 * j + 1], pi);
        }
        float t = pu * pi;
        #pragma unroll
        for (int m = 32; m >= 1; m >>= 1) t += __shfl_xor(t, m, 64);
        if (lane == 0) {
            t += bu[un] + bi[in - NU] + mu[0];
            out[p] = fminf(fmaxf(t, 1.0f), 5.0f);
        }
    }
}

extern "C" void kernel_launch(void* const* d_in, const int* in_sizes, int n_in,
                              void* d_out, int out_size, void* d_ws, size_t ws_size,
                              hipStream_t stream) {
    const int*   users = (const int*)d_in[0];
    const int*   items = (const int*)d_in[1];
    const int*   ei2   = (const int*)d_in[2];
    const float* ew    = (const float*)d_in[3];
    const float* U     = (const float*)d_in[4];
    const float* I     = (const float*)d_in[5];
    const float* W0    = (const float*)d_in[6];
    const float* b0    = (const float*)d_in[7];
    const float* g0    = (const float*)d_in[8];
    const float* be0   = (const float*)d_in[9];
    const float* W1    = (const float*)d_in[10];
    const float* b1    = (const float*)d_in[11];
    const float* g1    = (const float*)d_in[12];
    const float* be1   = (const float*)d_in[13];
    const float* Wp    = (const float*)d_in[14];
    const float* bp    = (const float*)d_in[15];
    const float* bu    = (const float*)d_in[16];
    const float* bi    = (const float*)d_in[17];
    const float* mu    = (const float*)d_in[18];

    int B = in_sizes[0];
    int E = in_sizes[2] / 2;
    const int* srcp = ei2;
    const int* dstp = ei2 + E;

    // workspace carve-up (256B aligned)
    char* p = (char*)d_ws;
    auto alloc = [&](size_t bytes) -> char* {
        char* r = p;
        p += (bytes + 255) & ~(size_t)255;
        return r;
    };
    int*    cbuf    = (int*)  alloc((size_t)(NBINS + 8) * 4);  // bincur|spillcnt|ovfcnt
    int*    bincur  = cbuf;
    int*    spillcnt= cbuf + NBINS;
    int*    ovfcnt  = cbuf + NBINS + 1;
    int*    cursor  = (int*)  alloc((size_t)NN * 4);
    float*  dinv    = (float*)alloc((size_t)NN * 4);
    int4*   ovf     = (int4*) alloc((size_t)OVF_MAX * 16);
    uint2*  spill   = (uint2*)alloc((size_t)SPILL_CAP * 8);      // 2.1 MB
    uchar*  cnt8    = (uchar*)alloc((size_t)BIN_BLOCKS * NBINS); // 0.45 MB
    uint2*  binbuf  = (uint2*)alloc((size_t)NBINS * BINCAP * 8); // 27.4 MB
    uint*   recs    = (uint*) alloc((size_t)NN * CAP * 4);       // 28.2 MB
    ushort* hw2b    = (ushort*)alloc((size_t)NN * D * 2);        // 19.2 MB
    uint*   h1b     = (uint*) alloc((size_t)NN * 32 * 4);        // 19.2 MB (bf16)
    const uint* hw2p = (const uint*)hw2b;
    // tail ALIASES [hw2b, h1b] (38.4 MB >= 28.8 MB needed): tail is written by
    // k_bin and dead after k_regroup; hw2b is first written by k_gemm1 (after
    // regroup) and h1b by k_conv1. Lifetimes are disjoint.
    uint2*  tail    = (uint2*)hw2b;   // BIN_BLOCKS*NBINS*8 records = 28.8 MB

    hipMemsetAsync(cbuf, 0, (size_t)(NBINS + 8) * 4, stream);

    int gW = (NN + 3) / 4;          // one wave per node, 4 waves/block

    // CSR build: bin -> regroup(+tails+spill+deg+dinv)
    k_bin<<<BIN_BLOCKS, 256, 0, stream>>>(srcp, dstp, ew, bincur, binbuf,
                                          spill, spillcnt, tail, cnt8, E);
    k_regroup<<<NBINS, 256, 0, stream>>>(bincur, binbuf, spill, spillcnt,
                                         tail, cnt8, recs, cursor, dinv,
                                         ovf, ovfcnt);

    // layer 1 (all nodes)
    k_gemm1<<<2048, 256, 0, stream>>>(U, I, W0, dinv, hw2b);
    k_conv1<<<gW, 256, 0, stream>>>(hw2p, cursor, recs, ovf, ovfcnt, dinv,
                                    b0, g0, be0, U, I, h1b);
    // layer 2: gemm all nodes (bf16 in), then fused sampled conv+proj+score
    k_gemm2<<<2048, 256, 0, stream>>>((const ushort*)h1b, W1, dinv, hw2b);
    k_conv2score<<<1024, 256, 0, stream>>>(hw2p, cursor, recs, ovf, ovfcnt, dinv,
                                           b1, g1, be1, users, items, h1b,
                                           Wp, bp, bu, bi, mu,
                                           (float*)d_out, B);
}

// Round 5
// 418.954 us; speedup vs baseline: 1.0438x; 1.0290x over previous
//
#include <hip/hip_runtime.h>

#define NU 100000
#define NI 50000
#define NN 150000   // NU + NI
#define D  64
#define CAP 47      // bucket capacity per dst; max in-degree ~44 for Poisson(21.3)
#define OVF_MAX 4096

// binning params (256-wide bins: regroup block reads exactly its own records)
#define BINSHIFT 8
#define BINW 256                 // dsts per bin
#define NBINS 586                // ceil(150000/256); 586*256 = 150016
#define BINCAP 5848              // per-bin record cap, mult of 8
#define STAGE_CAP 11             // LDS stage slots per bin (53.9KB -> 3 blocks/CU)
#define EPT 4                    // edges per thread per batch
#define SPILL_CAP 262144
#define BIN_BLOCKS 768           // 256 CUs x 3 blocks/CU, one round

typedef unsigned int uint;
typedef unsigned short ushort;
typedef unsigned char uchar;

// ---------------- helpers ----------------
__device__ __forceinline__ float half_reduce_add(float v) {  // reduce within 32-lane half
    #pragma unroll
    for (int m = 16; m >= 1; m >>= 1) v += __shfl_xor(v, m, 64);
    return v;
}
__device__ __forceinline__ ushort f2bf(float f) {   // round-to-nearest-even
    union { float f; uint i; } c; c.f = f;
    uint r = c.i + 0x7FFF + ((c.i >> 16) & 1);
    return (ushort)(r >> 16);
}
__device__ __forceinline__ float lane_bcast(float v, int l) {
    return __int_as_float(__builtin_amdgcn_readlane(__float_as_int(v), l));
}
// bf14 weight encoding: rounded top-14 bits of f32 (w in [0,1)); decode = 1 AND
__device__ __forceinline__ uint enc14(float w) {
    uint b = __float_as_uint(w) + 0x00020000u;   // round at bit 18
    return b & 0xFFFC0000u;
}
__device__ __forceinline__ float dec14(uint r) {
    return __uint_as_float(r & 0xFFFC0000u);
}
__device__ __forceinline__ void spill_one(int d, uint s, float w,
        uint2* __restrict__ spill, int* __restrict__ spillcnt) {
    int si = atomicAdd(spillcnt, 1);
    if (si < SPILL_CAP) spill[si] = make_uint2(s | enc14(w), (uint)d);
}

// ---------------- pass 1: LDS-staged binning, line-coalesced flushes ----------
// bin record: word0 = src18 | dlocal8<<18 ; word1 = float weight bits
// Residuals (<8 per bin) exit via a coalesced per-block tail dump (no atomics,
// no scalar scatter); k_regroup gathers them per-bin.
__global__ __launch_bounds__(256) void k_bin(
        const int* __restrict__ src, const int* __restrict__ dst,
        const float* __restrict__ ew, int* __restrict__ bincur,
        uint2* __restrict__ binbuf, uint2* __restrict__ spill,
        int* __restrict__ spillcnt, uint2* __restrict__ tail,
        uchar* __restrict__ cnt8, int E) {
    __shared__ uint2 stage[NBINS][STAGE_CAP];   // 51.6 KB -> 3 blocks/CU
    __shared__ int scnt[NBINS];
    int t = threadIdx.x;
    for (int i = t; i < NBINS; i += 256) scnt[i] = 0;
    __syncthreads();
    const int batch = 256 * EPT;
    for (int base = blockIdx.x * batch; base < E; base += BIN_BLOCKS * batch) {
        int dd[EPT]; uint ss[EPT]; float ww[EPT]; int ok[EPT];
        #pragma unroll
        for (int k = 0; k < EPT; ++k) {
            int e = base + k * 256 + t;
            ok[k] = (e < E);
            if (ok[k]) { dd[k] = dst[e]; ss[k] = (uint)src[e]; ww[k] = ew[e]; }
        }
        #pragma unroll
        for (int k = 0; k < EPT; ++k) {
            if (!ok[k]) continue;
            int bin = dd[k] >> BINSHIFT;
            int slot = atomicAdd(&scnt[bin], 1);
            if (slot < STAGE_CAP) {
                stage[bin][slot] = make_uint2(
                    ss[k] | ((uint)(dd[k] & (BINW - 1)) << 18),
                    (uint)__float_as_int(ww[k]));
            } else {
                spill_one(dd[k], ss[k], ww[k], spill, spillcnt);  // rare
            }
        }
        __syncthreads();
        for (int bin = t; bin < NBINS; bin += 256) {
            int c = scnt[bin]; if (c > STAGE_CAP) c = STAGE_CAP;
            while (c >= 8) {                // takes TOP 8, leaves bottom c-8
                int b0 = atomicAdd(&bincur[bin], 8);
                if (b0 + 8 <= BINCAP) {
                    uint4* o4 = (uint4*)(binbuf + (size_t)bin * BINCAP + b0);
                    uint2* s2 = &stage[bin][c - 8];
                    o4[0] = make_uint4(s2[0].x, s2[0].y, s2[1].x, s2[1].y);
                    o4[1] = make_uint4(s2[2].x, s2[2].y, s2[3].x, s2[3].y);
                    o4[2] = make_uint4(s2[4].x, s2[4].y, s2[5].x, s2[5].y);
                    o4[3] = make_uint4(s2[6].x, s2[6].y, s2[7].x, s2[7].y);
                } else {
                    for (int j = 0; j < 8; ++j) {
                        uint2 r = stage[bin][c - 8 + j];
                        spill_one((bin << BINSHIFT) + (int)(r.x >> 18),
                                  r.x & 0x3FFFFu, __int_as_float((int)r.y),
                                  spill, spillcnt);
                    }
                }
                c -= 8;
            }
            scnt[bin] = c;
        }
        __syncthreads();
    }
    // final residuals: c <= 7 per bin, in stage slots [0, c). Coalesced dump.
    uchar* cb = cnt8 + (size_t)blockIdx.x * NBINS;
    for (int i = t; i < NBINS; i += 256) cb[i] = (uchar)scnt[i];
    uint2* tb = tail + (size_t)blockIdx.x * (NBINS * 8);
    for (int i = t; i < NBINS * 8; i += 256) tb[i] = stage[i >> 3][i & 7];
}

// -------- pass 2: regroup + tails + spills + weighted degree + dinv -----------
__global__ __launch_bounds__(256) void k_regroup(
        const int* __restrict__ bincur, const uint2* __restrict__ binbuf,
        const uint2* __restrict__ spill, const int* __restrict__ spillcnt,
        const uint2* __restrict__ tail, const uchar* __restrict__ cnt8,
        uint* __restrict__ recs, int* __restrict__ cursor,
        float* __restrict__ dinv, int4* __restrict__ ovf,
        int* __restrict__ ovfcnt) {
    __shared__ uint image[256 * CAP];   // 47 KB, layout == recs layout
    __shared__ int cnt[256];
    __shared__ float ovfw[256];
    int t = threadIdx.x;
    int bin = blockIdx.x;
    cnt[t] = 0; ovfw[t] = 0.0f;
    __syncthreads();
    int dbase = bin << BINSHIFT;
    int nrec = bincur[bin]; if (nrec > BINCAP) nrec = BINCAP;
    const uint2* bb = binbuf + (size_t)bin * BINCAP;
    for (int i = t; i < nrec; i += 256) {
        uint2 r = bb[i];
        int dl = (int)(r.x >> 18);          // 8-bit dlocal, top bits zero
        int slot = atomicAdd(&cnt[dl], 1);
        uint s = r.x & 0x3FFFFu;
        float w = __int_as_float((int)r.y);
        if (slot < CAP) image[dl * CAP + slot] = enc14(w) | s;
        else {                                              // rare high-degree
            atomicAdd(&ovfw[dl], w);
            int o = atomicAdd(ovfcnt, 1);
            if (o < OVF_MAX)
                ovf[o] = make_int4(dbase + dl, (int)s, __float_as_int(w), 0);
        }
    }
    // per-block residual tails for this bin (~half of all records)
    for (int g = t; g < BIN_BLOCKS; g += 256) {
        int c = cnt8[(size_t)g * NBINS + bin];
        const uint2* tb = tail + ((size_t)g * NBINS + bin) * 8;
        for (int j = 0; j < c; ++j) {
            uint2 r = tb[j];
            int dl = (int)(r.x >> 18);
            int slot = atomicAdd(&cnt[dl], 1);
            uint s = r.x & 0x3FFFFu;
            float w = __int_as_float((int)r.y);
            if (slot < CAP) image[dl * CAP + slot] = enc14(w) | s;
            else {
                atomicAdd(&ovfw[dl], w);
                int o = atomicAdd(ovfcnt, 1);
                if (o < OVF_MAX)
                    ovf[o] = make_int4(dbase + dl, (int)s, __float_as_int(w), 0);
            }
        }
    }
    // spill entries (rare); spill words already bf14-encoded
    int ns = spillcnt[0]; if (ns > SPILL_CAP) ns = SPILL_CAP;
    for (int i = t; i < ns; i += 256) {
        uint2 e = spill[i];
        int d = (int)e.y;
        if (d < dbase || d >= dbase + BINW) continue;
        int dl = d - dbase;
        int slot = atomicAdd(&cnt[dl], 1);
        if (slot < CAP) image[dl * CAP + slot] = e.x;
        else {
            float w = dec14(e.x);
            atomicAdd(&ovfw[dl], w);
            int o = atomicAdd(ovfcnt, 1);
            if (o < OVF_MAX) ovf[o] = make_int4(d, (int)(e.x & 0x3FFFFu),
                                                __float_as_int(w), 0);
        }
    }
    __syncthreads();
    int ndl = NN - dbase; if (ndl > 256) ndl = 256;
    if (ndl <= 0) return;
    if (t < ndl) {
        int c = cnt[t];
        cursor[dbase + t] = c;
        if (c > CAP) c = CAP;
        float dg = ovfw[t];
        for (int j = 0; j < c; ++j) dg += dec14(image[t * CAP + j]);
        dinv[dbase + t] = rsqrtf(dg + 1.0f);   // self-loop weight 1 folded in
    }
    int tot = ndl * CAP;
    uint* out = recs + (size_t)dbase * CAP;
    for (int i = t; i < tot; i += 256) out[i] = image[i];  // fully coalesced
}

// ------- layer-1 GEMM: hw2b = bf16((x @ W0) * dinv), x = [U;I] f32 -----------
__global__ __launch_bounds__(256) void k_gemm1(
        const float* __restrict__ U, const float* __restrict__ I,
        const float* __restrict__ W, const float* __restrict__ dinv,
        ushort* __restrict__ out) {
    int lane = threadIdx.x & 63;
    float wreg[64];                         // column `lane` of W0
    #pragma unroll
    for (int k = 0; k < 64; ++k) wreg[k] = W[k * 64 + lane];
    int wpb = blockDim.x >> 6;
    int wid = blockIdx.x * wpb + (threadIdx.x >> 6);
    int tw = gridDim.x * wpb;
    for (int n = wid; n < NN; n += tw) {
        float xv = (n < NU) ? U[(size_t)n * D + lane]
                            : I[(size_t)(n - NU) * D + lane];
        float a0 = 0.f, a1 = 0.f, a2 = 0.f, a3 = 0.f;  // 4 chains (ILP)
        #pragma unroll
        for (int k = 0; k < 64; k += 4) {
            a0 = fmaf(lane_bcast(xv, k + 0), wreg[k + 0], a0);
            a1 = fmaf(lane_bcast(xv, k + 1), wreg[k + 1], a1);
            a2 = fmaf(lane_bcast(xv, k + 2), wreg[k + 2], a2);
            a3 = fmaf(lane_bcast(xv, k + 3), wreg[k + 3], a3);
        }
        out[(size_t)n * D + lane] = f2bf(((a0 + a1) + (a2 + a3)) * dinv[n]);
    }
}

// --- conv accumulate: ds_bpermute record broadcast; 12-gather UNCONDITIONAL
//     branch-free front (safe: lanes >= cnt carry rv=0 -> w=0, row-0 gather),
//     guarded pipelined tail for cnt > 24. R4's guarded front let the compiler
//     sink loads to uses (VGPR=20 proved ~4-deep); branch-free front pins MLP.
// hw2p = (const uint*)hw2b: row n = 32 dwords, dword p = bf16 feats (2p, 2p+1).
#define CA_DECL(c) uint x##c##0, x##c##1, x##c##2, x##c##3, \
                        w##c##0, w##c##1, w##c##2, w##c##3;
#define CA_GET(c, i, P, rvv) { \
    uint r = (uint)__builtin_amdgcn_ds_bpermute(vodd4 + 8 * (P), (int)(rvv)); \
    w##c##i = r & 0xFFFC0000u; \
    x##c##i = *(const uint*)((const char*)hw2p + \
                             (((r & 0x3FFFFu) << 7) + lb4)); }
#define CA_ISSUE(c, P0, rvv) { CA_GET(c, 0, (P0)+0, rvv) CA_GET(c, 1, (P0)+1, rvv) \
                               CA_GET(c, 2, (P0)+2, rvv) CA_GET(c, 3, (P0)+3, rvv) }
#define CA_FMA1(c, i, axv, ayv) { \
    axv = fmaf(__uint_as_float(w##c##i), __uint_as_float(x##c##i << 16), axv); \
    ayv = fmaf(__uint_as_float(w##c##i), \
               __uint_as_float(x##c##i & 0xFFFF0000u), ayv); }
#define CA_FMA(c, axv, ayv) { CA_FMA1(c,0,axv,ayv) CA_FMA1(c,1,axv,ayv) \
                              CA_FMA1(c,2,axv,ayv) CA_FMA1(c,3,axv,ayv) }

__device__ __forceinline__ float2 conv_accum2(int n, int lane,
        const uint* __restrict__ hw2p, const int* __restrict__ cursor,
        const uint* __restrict__ recs, const int4* __restrict__ ovf,
        const int* __restrict__ ovfcnt) {
    int cnt = __builtin_amdgcn_readfirstlane(cursor[n]);
    if (cnt > CAP) cnt = CAP;
    uint rv = (lane < cnt) ? recs[(size_t)n * CAP + lane] : 0u;
    const int  vodd4 = (lane >> 5) << 2;          // 0 or 4: even/odd edge half
    const uint lb4   = (uint)(lane & 31) << 2;    // byte offset within row
    uint xs = *(const uint*)((const char*)hw2p + (((uint)n << 7) + lb4));
    float ax = 0.f, ay = 0.f;
    int cp = (cnt + 7) & ~7;                      // 0..48, wave-uniform
    CA_DECL(A) CA_DECL(B) CA_DECL(G)
    // branch-free 12-deep front (covers cnt <= 24, i.e. most nodes)
    CA_ISSUE(A, 0, rv) CA_ISSUE(B, 4, rv) CA_ISSUE(G, 8, rv)
    CA_FMA(A, ax, ay)
    if (cp > 24) CA_ISSUE(A, 12, rv)
    CA_FMA(B, ax, ay)
    if (cp > 32) CA_ISSUE(B, 16, rv)
    CA_FMA(G, ax, ay)
    if (cp > 40) CA_ISSUE(G, 20, rv)
    if (cp > 24) CA_FMA(A, ax, ay)
    if (cp > 32) CA_FMA(B, ax, ay)
    if (cp > 40) CA_FMA(G, ax, ay)
    // combine even/odd halves
    ax += __shfl_xor(ax, 32, 64);
    ay += __shfl_xor(ay, 32, 64);
    // self-loop term
    ax += __uint_as_float(xs << 16);
    ay += __uint_as_float(xs & 0xFFFF0000u);
    // overflow list (normally empty)
    int novf = __builtin_amdgcn_readfirstlane(ovfcnt[0]);
    if (novf > 0) {
        if (novf > OVF_MAX) novf = OVF_MAX;
        for (int j = 0; j < novf; ++j) {
            int4 e = ovf[j];
            if (e.x == n) {
                float w = __int_as_float(e.z);
                uint x = hw2p[(size_t)e.y * 32 + (lane & 31)];
                ax = fmaf(w, __int_as_float((int)(x << 16)), ax);
                ay = fmaf(w, __int_as_float((int)(x & 0xFFFF0000u)), ay);
            }
        }
    }
    return make_float2(ax, ay);
}

// --- dual-node conv accumulate for k_conv2score: user & item pipelines
//     interleaved -> 24 gathers in flight, independent streams ---------------
#define CB_DECL(p, c) uint p##x##c##0, p##x##c##1, p##x##c##2, p##x##c##3, \
                           p##w##c##0, p##w##c##1, p##w##c##2, p##w##c##3;
#define CB_GET(p, c, i, P, rvv) { \
    uint r = (uint)__builtin_amdgcn_ds_bpermute(vodd4 + 8 * (P), (int)(rvv)); \
    p##w##c##i = r & 0xFFFC0000u; \
    p##x##c##i = *(const uint*)((const char*)hw2p + \
                                (((r & 0x3FFFFu) << 7) + lb4)); }
#define CB_ISSUE(p, c, P0, rvv) { CB_GET(p,c,0,(P0)+0,rvv) CB_GET(p,c,1,(P0)+1,rvv) \
                                  CB_GET(p,c,2,(P0)+2,rvv) CB_GET(p,c,3,(P0)+3,rvv) }
#define CB_FMA1(p, c, i, axv, ayv) { \
    axv = fmaf(__uint_as_float(p##w##c##i), \
               __uint_as_float(p##x##c##i << 16), axv); \
    ayv = fmaf(__uint_as_float(p##w##c##i), \
               __uint_as_float(p##x##c##i & 0xFFFF0000u), ayv); }
#define CB_FMA(p, c, axv, ayv) { CB_FMA1(p,c,0,axv,ayv) CB_FMA1(p,c,1,axv,ayv) \
                                 CB_FMA1(p,c,2,axv,ayv) CB_FMA1(p,c,3,axv,ayv) }

__device__ __forceinline__ void conv_accum2_dual(int nu, int ni, int lane,
        const uint* __restrict__ hw2p, const int* __restrict__ cursor,
        const uint* __restrict__ recs, const int4* __restrict__ ovf,
        const int* __restrict__ ovfcnt, float2* outu, float2* outi) {
    int cu = __builtin_amdgcn_readfirstlane(cursor[nu]); if (cu > CAP) cu = CAP;
    int ci = __builtin_amdgcn_readfirstlane(cursor[ni]); if (ci > CAP) ci = CAP;
    uint rvu = (lane < cu) ? recs[(size_t)nu * CAP + lane] : 0u;
    uint rvi = (lane < ci) ? recs[(size_t)ni * CAP + lane] : 0u;
    const int  vodd4 = (lane >> 5) << 2;
    const uint lb4   = (uint)(lane & 31) << 2;
    uint xsu = *(const uint*)((const char*)hw2p + (((uint)nu << 7) + lb4));
    uint xsi = *(const uint*)((const char*)hw2p + (((uint)ni << 7) + lb4));
    float uax = 0.f, uay = 0.f, iax = 0.f, iay = 0.f;
    int cpu_ = (cu + 7) & ~7, cpi_ = (ci + 7) & ~7;
    CB_DECL(u, A) CB_DECL(u, B) CB_DECL(u, G)
    CB_DECL(i, A) CB_DECL(i, B) CB_DECL(i, G)
    CB_ISSUE(u, A, 0, rvu) CB_ISSUE(i, A, 0, rvi)
    CB_ISSUE(u, B, 4, rvu) CB_ISSUE(i, B, 4, rvi)
    CB_ISSUE(u, G, 8, rvu) CB_ISSUE(i, G, 8, rvi)
    CB_FMA(u, A, uax, uay) CB_FMA(i, A, iax, iay)
    if (cpu_ > 24) CB_ISSUE(u, A, 12, rvu)
    if (cpi_ > 24) CB_ISSUE(i, A, 12, rvi)
    CB_FMA(u, B, uax, uay) CB_FMA(i, B, iax, iay)
    if (cpu_ > 32) CB_ISSUE(u, B, 16, rvu)
    if (cpi_ > 32) CB_ISSUE(i, B, 16, rvi)
    CB_FMA(u, G, uax, uay) CB_FMA(i, G, iax, iay)
    if (cpu_ > 40) CB_ISSUE(u, G, 20, rvu)
    if (cpi_ > 40) CB_ISSUE(i, G, 20, rvi)
    if (cpu_ > 24) CB_FMA(u, A, uax, uay)
    if (cpi_ > 24) CB_FMA(i, A, iax, iay)
    if (cpu_ > 32) CB_FMA(u, B, uax, uay)
    if (cpi_ > 32) CB_FMA(i, B, iax, iay)
    if (cpu_ > 40) CB_FMA(u, G, uax, uay)
    if (cpi_ > 40) CB_FMA(i, G, iax, iay)
    uax += __shfl_xor(uax, 32, 64); uay += __shfl_xor(uay, 32, 64);
    iax += __shfl_xor(iax, 32, 64); iay += __shfl_xor(iay, 32, 64);
    uax += __uint_as_float(xsu << 16); uay += __uint_as_float(xsu & 0xFFFF0000u);
    iax += __uint_as_float(xsi << 16); iay += __uint_as_float(xsi & 0xFFFF0000u);
    int novf = __builtin_amdgcn_readfirstlane(ovfcnt[0]);
    if (novf > 0) {
        if (novf > OVF_MAX) novf = OVF_MAX;
        for (int j = 0; j < novf; ++j) {
            int4 e = ovf[j];
            if (e.x == nu || e.x == ni) {
                float w = __int_as_float(e.z);
                uint x = hw2p[(size_t)e.y * 32 + (lane & 31)];
                float fx = __uint_as_float(x << 16);
                float fy = __uint_as_float(x & 0xFFFF0000u);
                if (e.x == nu) { uax = fmaf(w, fx, uax); uay = fmaf(w, fy, uay); }
                else           { iax = fmaf(w, fx, iax); iay = fmaf(w, fy, iay); }
            }
        }
    }
    *outu = make_float2(uax, uay);
    *outi = make_float2(iax, iay);
}

// bias + LN + ReLU on pair layout; returns (y0,y1) for feats (2p, 2p+1)
__device__ __forceinline__ float2 ln_relu2(float2 a, float di, int p,
        const float* __restrict__ b, const float* __restrict__ g,
        const float* __restrict__ be) {
    float2 bb = ((const float2*)b)[p];
    float v0 = fmaf(a.x, di, bb.x);
    float v1 = fmaf(a.y, di, bb.y);
    float m = half_reduce_add(v0 + v1) * (1.0f / 64.0f);
    float d0 = v0 - m, d1 = v1 - m;
    float var = half_reduce_add(d0 * d0 + d1 * d1) * (1.0f / 64.0f);
    float rs = rsqrtf(var + 1e-5f);
    float2 gg = ((const float2*)g)[p];
    float2 ee = ((const float2*)be)[p];
    return make_float2(fmaxf(fmaf(d0 * rs, gg.x, ee.x), 0.0f),
                       fmaxf(fmaf(d1 * rs, gg.y, ee.y), 0.0f));
}

// --- layer-1 conv (all nodes) + bias + LN + ReLU + residual; h1 out in bf16 --
__global__ __launch_bounds__(256) void k_conv1(
        const uint* __restrict__ hw2p, const int* __restrict__ cursor,
        const uint* __restrict__ recs, const int4* __restrict__ ovf,
        const int* __restrict__ ovfcnt, const float* __restrict__ dinv,
        const float* __restrict__ b, const float* __restrict__ g,
        const float* __restrict__ be, const float* __restrict__ U,
        const float* __restrict__ I, uint* __restrict__ out1) {
    int lane = threadIdx.x & 63;
    int n = __builtin_amdgcn_readfirstlane(blockIdx.x * 4 + (threadIdx.x >> 6));
    if (n >= NN) return;
    float2 a = conv_accum2(n, lane, hw2p, cursor, recs, ovf, ovfcnt);
    int p = lane & 31;
    float2 y = ln_relu2(a, dinv[n], p, b, g, be);
    const float* R = (n < NU) ? (U + (size_t)n * D) : (I + (size_t)(n - NU) * D);
    float2 rr = ((const float2*)R)[p];
    if (lane < 32) {
        out1[(size_t)n * 32 + p] =
            (uint)f2bf(y.x + rr.x) | ((uint)f2bf(y.y + rr.y) << 16);
    }
}

// ------- layer-2 GEMM: hw2b = bf16((h1 @ W1) * dinv), h1 read as bf16 --------
__global__ __launch_bounds__(256) void k_gemm2(
        const ushort* __restrict__ hb, const float* __restrict__ W,
        const float* __restrict__ dinv, ushort* __restrict__ out) {
    int lane = threadIdx.x & 63;
    float wreg[64];                         // column `lane` of W1
    #pragma unroll
    for (int k = 0; k < 64; ++k) wreg[k] = W[k * 64 + lane];
    int wpb = blockDim.x >> 6;
    int wid = blockIdx.x * wpb + (threadIdx.x >> 6);
    int tw = gridDim.x * wpb;
    for (int n = wid; n < NN; n += tw) {
        float xv = __uint_as_float((uint)hb[(size_t)n * D + lane] << 16);
        float a0 = 0.f, a1 = 0.f, a2 = 0.f, a3 = 0.f;
        #pragma unroll
        for (int k = 0; k < 64; k += 4) {
            a0 = fmaf(lane_bcast(xv, k + 0), wreg[k + 0], a0);
            a1 = fmaf(lane_bcast(xv, k + 1), wreg[k + 1], a1);
            a2 = fmaf(lane_bcast(xv, k + 2), wreg[k + 2], a2);
            a3 = fmaf(lane_bcast(xv, k + 3), wreg[k + 3], a3);
        }
        out[(size_t)n * D + lane] = f2bf(((a0 + a1) + (a2 + a3)) * dinv[n]);
    }
}

// ------- FUSED layer-2 conv (sampled) + projection + scoring ------------------
// Wp lives in LDS (frees ~64 VGPRs -> occupancy for the latency-bound conv);
// user & item convs run as one interleaved dual pipeline (2x MLP).
__global__ __launch_bounds__(256) void k_conv2score(
        const uint* __restrict__ hw2p, const int* __restrict__ cursor,
        const uint* __restrict__ recs, const int4* __restrict__ ovf,
        const int* __restrict__ ovfcnt, const float* __restrict__ dinv,
        const float* __restrict__ b, const float* __restrict__ g,
        const float* __restrict__ be, const int* __restrict__ users,
        const int* __restrict__ items, const uint* __restrict__ h1b,
        const float* __restrict__ Wp, const float* __restrict__ bp,
        const float* __restrict__ bu, const float* __restrict__ bi,
        const float* __restrict__ mu, float* __restrict__ out, int B) {
    __shared__ float wlds[64 * 64];        // Wp, 16 KB
    int t = threadIdx.x;
    for (int i = t; i < 64 * 64; i += 256) wlds[i] = Wp[i];
    __syncthreads();
    int lane = t & 63;
    float bpl = bp[lane];
    int q = lane & 31;
    int wpb = blockDim.x >> 6;
    int wid = blockIdx.x * wpb + (t >> 6);
    int tw = gridDim.x * wpb;
    for (int p = wid; p < B; p += tw) {
        int un = users[p];
        int in_ = NU + items[p];
        int nu = __builtin_amdgcn_readfirstlane(un);
        int ni = __builtin_amdgcn_readfirstlane(in_);
        float2 au, ai;
        conv_accum2_dual(nu, ni, lane, hw2p, cursor, recs, ovf, ovfcnt,
                         &au, &ai);
        float2 yu = ln_relu2(au, dinv[nu], q, b, g, be);
        float2 yi = ln_relu2(ai, dinv[ni], q, b, g, be);
        uint xu = h1b[(size_t)nu * 32 + q];
        uint xi = h1b[(size_t)ni * 32 + q];
        float2 hu = make_float2(yu.x + __uint_as_float(xu << 16),
                                yu.y + __uint_as_float(xu & 0xFFFF0000u));
        float2 hi = make_float2(yi.x + __uint_as_float(xi << 16),
                                yi.y + __uint_as_float(xi & 0xFFFF0000u));
        // --- projection (feat 2j from .x, 2j+1 from .y) + dot
        float pu = bpl, pi = bpl;
        #pragma unroll
        for (int j = 0; j < 32; ++j) {
            float w0 = wlds[(2 * j) * 64 + lane];
            float w1 = wlds[(2 * j + 1) * 64 + lane];
            pu = fmaf(lane_bcast(hu.x, j), w0, pu);
            pu = fmaf(lane_bcast(hu.y, j), w1, pu);
            pi = fmaf(lane_bcast(hi.x, j), w0, pi);
            pi = fmaf(lane_bcast(hi.y, j), w1, pi);
        }
        float dot = pu * pi;
        #pragma unroll
        for (int m = 32; m >= 1; m >>= 1) dot += __shfl_xor(dot, m, 64);
        if (lane == 0) {
            dot += bu[un] + bi[in_ - NU] + mu[0];
            out[p] = fminf(fmaxf(dot, 1.0f), 5.0f);
        }
    }
}

extern "C" void kernel_launch(void* const* d_in, const int* in_sizes, int n_in,
                              void* d_out, int out_size, void* d_ws, size_t ws_size,
                              hipStream_t stream) {
    const int*   users = (const int*)d_in[0];
    const int*   items = (const int*)d_in[1];
    const int*   ei2   = (const int*)d_in[2];
    const float* ew    = (const float*)d_in[3];
    const float* U     = (const float*)d_in[4];
    const float* I     = (const float*)d_in[5];
    const float* W0    = (const float*)d_in[6];
    const float* b0    = (const float*)d_in[7];
    const float* g0    = (const float*)d_in[8];
    const float* be0   = (const float*)d_in[9];
    const float* W1    = (const float*)d_in[10];
    const float* b1    = (const float*)d_in[11];
    const float* g1    = (const float*)d_in[12];
    const float* be1   = (const float*)d_in[13];
    const float* Wp    = (const float*)d_in[14];
    const float* bp    = (const float*)d_in[15];
    const float* bu    = (const float*)d_in[16];
    const float* bi    = (const float*)d_in[17];
    const float* mu    = (const float*)d_in[18];

    int B = in_sizes[0];
    int E = in_sizes[2] / 2;
    const int* srcp = ei2;
    const int* dstp = ei2 + E;

    // workspace carve-up (256B aligned)
    char* p = (char*)d_ws;
    auto alloc = [&](size_t bytes) -> char* {
        char* r = p;
        p += (bytes + 255) & ~(size_t)255;
        return r;
    };
    int*    cbuf    = (int*)  alloc((size_t)(NBINS + 8) * 4);  // bincur|spillcnt|ovfcnt
    int*    bincur  = cbuf;
    int*    spillcnt= cbuf + NBINS;
    int*    ovfcnt  = cbuf + NBINS + 1;
    int*    cursor  = (int*)  alloc((size_t)NN * 4);
    float*  dinv    = (float*)alloc((size_t)NN * 4);
    int4*   ovf     = (int4*) alloc((size_t)OVF_MAX * 16);
    uint2*  spill   = (uint2*)alloc((size_t)SPILL_CAP * 8);      // 2.1 MB
    uchar*  cnt8    = (uchar*)alloc((size_t)BIN_BLOCKS * NBINS); // 0.45 MB
    uint2*  binbuf  = (uint2*)alloc((size_t)NBINS * BINCAP * 8); // 27.4 MB
    uint*   recs    = (uint*) alloc((size_t)NN * CAP * 4);       // 28.2 MB
    ushort* hw2b    = (ushort*)alloc((size_t)NN * D * 2);        // 19.2 MB
    uint*   h1b     = (uint*) alloc((size_t)NN * 32 * 4);        // 19.2 MB (bf16)
    const uint* hw2p = (const uint*)hw2b;
    // tail ALIASES [hw2b, h1b] (38.4 MB >= 28.8 MB needed): tail is written by
    // k_bin and dead after k_regroup; hw2b is first written by k_gemm1 (after
    // regroup) and h1b by k_conv1. Lifetimes are disjoint.
    uint2*  tail    = (uint2*)hw2b;   // BIN_BLOCKS*NBINS*8 records = 28.8 MB

    hipMemsetAsync(cbuf, 0, (size_t)(NBINS + 8) * 4, stream);

    int gW = (NN + 3) / 4;          // one wave per node, 4 waves/block

    // CSR build: bin -> regroup(+tails+spill+deg+dinv)
    k_bin<<<BIN_BLOCKS, 256, 0, stream>>>(srcp, dstp, ew, bincur, binbuf,
                                          spill, spillcnt, tail, cnt8, E);
    k_regroup<<<NBINS, 256, 0, stream>>>(bincur, binbuf, spill, spillcnt,
                                         tail, cnt8, recs, cursor, dinv,
                                         ovf, ovfcnt);

    // layer 1 (all nodes)
    k_gemm1<<<2048, 256, 0, stream>>>(U, I, W0, dinv, hw2b);
    k_conv1<<<gW, 256, 0, stream>>>(hw2p, cursor, recs, ovf, ovfcnt, dinv,
                                    b0, g0, be0, U, I, h1b);
    // layer 2: gemm all nodes (bf16 in), then fused sampled conv+proj+score
    k_gemm2<<<2048, 256, 0, stream>>>((const ushort*)h1b, W1, dinv, hw2b);
    k_conv2score<<<2048, 256, 0, stream>>>(hw2p, cursor, recs, ovf, ovfcnt, dinv,
                                           b1, g1, be1, users, items, h1b,
                                           Wp, bp, bu, bi, mu,
                                           (float*)d_out, B);
}

// Round 6
// 403.041 us; speedup vs baseline: 1.0850x; 1.0395x over previous
//
#include <hip/hip_runtime.h>

#define NU 100000
#define NI 50000
#define NN 150000   // NU + NI
#define D  64
#define CAP 47      // bucket capacity per dst; max in-degree ~44 for Poisson(21.3)
#define OVF_MAX 4096

// binning params (256-wide bins: regroup block reads exactly its own records)
#define BINSHIFT 8
#define BINW 256                 // dsts per bin
#define NBINS 586                // ceil(150000/256); 586*256 = 150016
#define BINCAP 5848              // per-bin record cap, mult of 8
#define STAGE_CAP 11             // LDS stage slots per bin (53.9KB -> 3 blocks/CU)
#define EPT 4                    // edges per thread per batch
#define SPILL_CAP 262144
#define BIN_BLOCKS 768           // 256 CUs x 3 blocks/CU, one round
#define BCPAD 16                 // bincur stride: 1 word per 64B cacheline
                                 // (R5: 586 hot atomics words in 37 lines ->
                                 //  per-LINE serialization at the coherence
                                 //  point was k_bin's 75us @ 3% VALU)

typedef unsigned int uint;
typedef unsigned short ushort;
typedef unsigned char uchar;

// ---------------- helpers ----------------
__device__ __forceinline__ float half_reduce_add(float v) {  // reduce within 32-lane half
    #pragma unroll
    for (int m = 16; m >= 1; m >>= 1) v += __shfl_xor(v, m, 64);
    return v;
}
__device__ __forceinline__ float quad_reduce_add(float v) {  // reduce within 16-lane group
    #pragma unroll
    for (int m = 8; m >= 1; m >>= 1) v += __shfl_xor(v, m, 64);
    return v;
}
__device__ __forceinline__ ushort f2bf(float f) {   // round-to-nearest-even
    union { float f; uint i; } c; c.f = f;
    uint r = c.i + 0x7FFF + ((c.i >> 16) & 1);
    return (ushort)(r >> 16);
}
__device__ __forceinline__ float lane_bcast(float v, int l) {
    return __int_as_float(__builtin_amdgcn_readlane(__float_as_int(v), l));
}
// bf14 weight encoding: rounded top-14 bits of f32 (w in [0,1)); decode = 1 AND
__device__ __forceinline__ uint enc14(float w) {
    uint b = __float_as_uint(w) + 0x00020000u;   // round at bit 18
    return b & 0xFFFC0000u;
}
__device__ __forceinline__ float dec14(uint r) {
    return __uint_as_float(r & 0xFFFC0000u);
}
__device__ __forceinline__ void spill_one(int d, uint s, float w,
        uint2* __restrict__ spill, int* __restrict__ spillcnt) {
    int si = atomicAdd(spillcnt, 1);
    if (si < SPILL_CAP) spill[si] = make_uint2(s | enc14(w), (uint)d);
}

// ---------------- pass 1: LDS-staged binning, line-coalesced flushes ----------
// bin record: word0 = src18 | dlocal8<<18 ; word1 = float weight bits
// Residuals (<8 per bin) exit via a coalesced per-block tail dump (no atomics);
// bincur is cacheline-padded (BCPAD) to break atomic line contention.
__global__ __launch_bounds__(256) void k_bin(
        const int* __restrict__ src, const int* __restrict__ dst,
        const float* __restrict__ ew, int* __restrict__ bincur,
        uint2* __restrict__ binbuf, uint2* __restrict__ spill,
        int* __restrict__ spillcnt, uint2* __restrict__ tail,
        uchar* __restrict__ cnt8, int E) {
    __shared__ uint2 stage[NBINS][STAGE_CAP];   // 51.6 KB -> 3 blocks/CU
    __shared__ int scnt[NBINS];
    int t = threadIdx.x;
    for (int i = t; i < NBINS; i += 256) scnt[i] = 0;
    __syncthreads();
    const int batch = 256 * EPT;
    for (int base = blockIdx.x * batch; base < E; base += BIN_BLOCKS * batch) {
        int dd[EPT]; uint ss[EPT]; float ww[EPT]; int ok[EPT];
        #pragma unroll
        for (int k = 0; k < EPT; ++k) {
            int e = base + k * 256 + t;
            ok[k] = (e < E);
            if (ok[k]) { dd[k] = dst[e]; ss[k] = (uint)src[e]; ww[k] = ew[e]; }
        }
        #pragma unroll
        for (int k = 0; k < EPT; ++k) {
            if (!ok[k]) continue;
            int bin = dd[k] >> BINSHIFT;
            int slot = atomicAdd(&scnt[bin], 1);
            if (slot < STAGE_CAP) {
                stage[bin][slot] = make_uint2(
                    ss[k] | ((uint)(dd[k] & (BINW - 1)) << 18),
                    (uint)__float_as_int(ww[k]));
            } else {
                spill_one(dd[k], ss[k], ww[k], spill, spillcnt);  // rare
            }
        }
        __syncthreads();
        for (int bin = t; bin < NBINS; bin += 256) {
            int c = scnt[bin]; if (c > STAGE_CAP) c = STAGE_CAP;
            while (c >= 8) {                // takes TOP 8, leaves bottom c-8
                int b0 = atomicAdd(&bincur[bin * BCPAD], 8);
                if (b0 + 8 <= BINCAP) {
                    uint4* o4 = (uint4*)(binbuf + (size_t)bin * BINCAP + b0);
                    uint2* s2 = &stage[bin][c - 8];
                    o4[0] = make_uint4(s2[0].x, s2[0].y, s2[1].x, s2[1].y);
                    o4[1] = make_uint4(s2[2].x, s2[2].y, s2[3].x, s2[3].y);
                    o4[2] = make_uint4(s2[4].x, s2[4].y, s2[5].x, s2[5].y);
                    o4[3] = make_uint4(s2[6].x, s2[6].y, s2[7].x, s2[7].y);
                } else {
                    for (int j = 0; j < 8; ++j) {
                        uint2 r = stage[bin][c - 8 + j];
                        spill_one((bin << BINSHIFT) + (int)(r.x >> 18),
                                  r.x & 0x3FFFFu, __int_as_float((int)r.y),
                                  spill, spillcnt);
                    }
                }
                c -= 8;
            }
            scnt[bin] = c;
        }
        __syncthreads();
    }
    // final residuals: c <= 7 per bin, in stage slots [0, c). Coalesced dump.
    uchar* cb = cnt8 + (size_t)blockIdx.x * NBINS;
    for (int i = t; i < NBINS; i += 256) cb[i] = (uchar)scnt[i];
    uint2* tb = tail + (size_t)blockIdx.x * (NBINS * 8);
    for (int i = t; i < NBINS * 8; i += 256) tb[i] = stage[i >> 3][i & 7];
}

// -------- pass 2: regroup + tails + spills + weighted degree + dinv -----------
__global__ __launch_bounds__(256) void k_regroup(
        const int* __restrict__ bincur, const uint2* __restrict__ binbuf,
        const uint2* __restrict__ spill, const int* __restrict__ spillcnt,
        const uint2* __restrict__ tail, const uchar* __restrict__ cnt8,
        uint* __restrict__ recs, int* __restrict__ cursor,
        float* __restrict__ dinv, int4* __restrict__ ovf,
        int* __restrict__ ovfcnt) {
    __shared__ uint image[256 * CAP];   // 47 KB, layout == recs layout
    __shared__ int cnt[256];
    __shared__ float ovfw[256];
    int t = threadIdx.x;
    int bin = blockIdx.x;
    cnt[t] = 0; ovfw[t] = 0.0f;
    __syncthreads();
    int dbase = bin << BINSHIFT;
    int nrec = bincur[bin * BCPAD]; if (nrec > BINCAP) nrec = BINCAP;
    const uint2* bb = binbuf + (size_t)bin * BINCAP;
    for (int i = t; i < nrec; i += 256) {
        uint2 r = bb[i];
        int dl = (int)(r.x >> 18);          // 8-bit dlocal, top bits zero
        int slot = atomicAdd(&cnt[dl], 1);
        uint s = r.x & 0x3FFFFu;
        float w = __int_as_float((int)r.y);
        if (slot < CAP) image[dl * CAP + slot] = enc14(w) | s;
        else {                                              // rare high-degree
            atomicAdd(&ovfw[dl], w);
            int o = atomicAdd(ovfcnt, 1);
            if (o < OVF_MAX)
                ovf[o] = make_int4(dbase + dl, (int)s, __float_as_int(w), 0);
        }
    }
    // per-block residual tails for this bin (~half of all records)
    for (int g = t; g < BIN_BLOCKS; g += 256) {
        int c = cnt8[(size_t)g * NBINS + bin];
        const uint2* tb = tail + ((size_t)g * NBINS + bin) * 8;
        for (int j = 0; j < c; ++j) {
            uint2 r = tb[j];
            int dl = (int)(r.x >> 18);
            int slot = atomicAdd(&cnt[dl], 1);
            uint s = r.x & 0x3FFFFu;
            float w = __int_as_float((int)r.y);
            if (slot < CAP) image[dl * CAP + slot] = enc14(w) | s;
            else {
                atomicAdd(&ovfw[dl], w);
                int o = atomicAdd(ovfcnt, 1);
                if (o < OVF_MAX)
                    ovf[o] = make_int4(dbase + dl, (int)s, __float_as_int(w), 0);
            }
        }
    }
    // spill entries (rare); spill words already bf14-encoded
    int ns = spillcnt[0]; if (ns > SPILL_CAP) ns = SPILL_CAP;
    for (int i = t; i < ns; i += 256) {
        uint2 e = spill[i];
        int d = (int)e.y;
        if (d < dbase || d >= dbase + BINW) continue;
        int dl = d - dbase;
        int slot = atomicAdd(&cnt[dl], 1);
        if (slot < CAP) image[dl * CAP + slot] = e.x;
        else {
            float w = dec14(e.x);
            atomicAdd(&ovfw[dl], w);
            int o = atomicAdd(ovfcnt, 1);
            if (o < OVF_MAX) ovf[o] = make_int4(d, (int)(e.x & 0x3FFFFu),
                                                __float_as_int(w), 0);
        }
    }
    __syncthreads();
    int ndl = NN - dbase; if (ndl > 256) ndl = 256;
    if (ndl <= 0) return;
    if (t < ndl) {
        int c = cnt[t];
        cursor[dbase + t] = c;
        if (c > CAP) c = CAP;
        float dg = ovfw[t];
        for (int j = 0; j < c; ++j) dg += dec14(image[t * CAP + j]);
        dinv[dbase + t] = rsqrtf(dg + 1.0f);   // self-loop weight 1 folded in
    }
    int tot = ndl * CAP;
    uint* out = recs + (size_t)dbase * CAP;
    for (int i = t; i < tot; i += 256) out[i] = image[i];  // fully coalesced
}

// ------- layer-1 GEMM: hw2b = bf16((x @ W0) * dinv), x = [U;I] f32 -----------
__global__ __launch_bounds__(256) void k_gemm1(
        const float* __restrict__ U, const float* __restrict__ I,
        const float* __restrict__ W, const float* __restrict__ dinv,
        ushort* __restrict__ out) {
    int lane = threadIdx.x & 63;
    float wreg[64];                         // column `lane` of W0
    #pragma unroll
    for (int k = 0; k < 64; ++k) wreg[k] = W[k * 64 + lane];
    int wpb = blockDim.x >> 6;
    int wid = blockIdx.x * wpb + (threadIdx.x >> 6);
    int tw = gridDim.x * wpb;
    for (int n = wid; n < NN; n += tw) {
        float xv = (n < NU) ? U[(size_t)n * D + lane]
                            : I[(size_t)(n - NU) * D + lane];
        float a0 = 0.f, a1 = 0.f, a2 = 0.f, a3 = 0.f;  // 4 chains (ILP)
        #pragma unroll
        for (int k = 0; k < 64; k += 4) {
            a0 = fmaf(lane_bcast(xv, k + 0), wreg[k + 0], a0);
            a1 = fmaf(lane_bcast(xv, k + 1), wreg[k + 1], a1);
            a2 = fmaf(lane_bcast(xv, k + 2), wreg[k + 2], a2);
            a3 = fmaf(lane_bcast(xv, k + 3), wreg[k + 3], a3);
        }
        out[(size_t)n * D + lane] = f2bf(((a0 + a1) + (a2 + a3)) * dinv[n]);
    }
}

// --- QUAD conv accumulate (k_conv1): each lane gathers dwordx2 (8B), 16 lanes
//     cover a row -> one bpermute + one addr + one load serves 4 edges (vs 2),
//     halving per-edge overhead; FMA count (64 MAC/edge) unchanged. Lane q=
//     lane&15 accumulates feats 4q..4q+3. Branch-free 24-edge front.
#define CQ_DECL(c) uint2 x##c##0, x##c##1; uint w##c##0, w##c##1;
#define CQ_GET(c, i, P, rvv) { \
    uint r = (uint)__builtin_amdgcn_ds_bpermute(vg4 + 4 * (P), (int)(rvv)); \
    w##c##i = r & 0xFFFC0000u; \
    x##c##i = *(const uint2*)((const char*)hw2p + \
                              (((r & 0x3FFFFu) << 7) + lb8)); }
#define CQ_ISSUE(c, P0, rvv) { CQ_GET(c, 0, (P0), rvv) CQ_GET(c, 1, (P0)+4, rvv) }
#define CQ_FMA1(c, i) { \
    float wf = __uint_as_float(w##c##i); \
    ax = fmaf(wf, __uint_as_float(x##c##i.x << 16), ax); \
    ay = fmaf(wf, __uint_as_float(x##c##i.x & 0xFFFF0000u), ay); \
    az = fmaf(wf, __uint_as_float(x##c##i.y << 16), az); \
    aw = fmaf(wf, __uint_as_float(x##c##i.y & 0xFFFF0000u), aw); }
#define CQ_FMA(c) { CQ_FMA1(c, 0) CQ_FMA1(c, 1) }

// --- layer-1 conv (all nodes) + bias + LN + ReLU + residual; h1 out in bf16
//     (linear feat order preserved -> gemm2/conv2score untouched) ------------
__global__ __launch_bounds__(256) void k_conv1(
        const uint* __restrict__ hw2p, const int* __restrict__ cursor,
        const uint* __restrict__ recs, const int4* __restrict__ ovf,
        const int* __restrict__ ovfcnt, const float* __restrict__ dinv,
        const float* __restrict__ b, const float* __restrict__ g,
        const float* __restrict__ be, const float* __restrict__ U,
        const float* __restrict__ I, uint* __restrict__ out1) {
    int lane = threadIdx.x & 63;
    int n = __builtin_amdgcn_readfirstlane(blockIdx.x * 4 + (threadIdx.x >> 6));
    if (n >= NN) return;
    int cnt = __builtin_amdgcn_readfirstlane(cursor[n]);
    if (cnt > CAP) cnt = CAP;
    uint rv = (lane < cnt) ? recs[(size_t)n * CAP + lane] : 0u;
    const int  vg4 = (lane >> 4) << 2;            // group 0..3 -> record P+g
    const uint lb8 = (uint)(lane & 15) << 3;      // byte offset within row
    uint2 xs = *(const uint2*)((const char*)hw2p + (((uint)n << 7) + lb8));
    float ax = 0.f, ay = 0.f, az = 0.f, aw = 0.f;
    int cp = (cnt + 7) & ~7;                      // 0..48, wave-uniform
    CQ_DECL(A) CQ_DECL(B) CQ_DECL(G)
    // branch-free 24-edge front (covers cnt <= 24, i.e. most nodes)
    CQ_ISSUE(A, 0, rv) CQ_ISSUE(B, 8, rv) CQ_ISSUE(G, 16, rv)
    CQ_FMA(A)
    if (cp > 24) CQ_ISSUE(A, 24, rv)
    CQ_FMA(B)
    if (cp > 32) CQ_ISSUE(B, 32, rv)
    CQ_FMA(G)
    if (cp > 40) CQ_ISSUE(G, 40, rv)
    if (cp > 24) CQ_FMA(A)
    if (cp > 32) CQ_FMA(B)
    if (cp > 40) CQ_FMA(G)
    // combine the 4 groups (lanes q, q+16, q+32, q+48 hold partials)
    ax += __shfl_xor(ax, 32, 64); ax += __shfl_xor(ax, 16, 64);
    ay += __shfl_xor(ay, 32, 64); ay += __shfl_xor(ay, 16, 64);
    az += __shfl_xor(az, 32, 64); az += __shfl_xor(az, 16, 64);
    aw += __shfl_xor(aw, 32, 64); aw += __shfl_xor(aw, 16, 64);
    // self-loop term
    ax += __uint_as_float(xs.x << 16);
    ay += __uint_as_float(xs.x & 0xFFFF0000u);
    az += __uint_as_float(xs.y << 16);
    aw += __uint_as_float(xs.y & 0xFFFF0000u);
    // overflow list (normally empty)
    int novf = __builtin_amdgcn_readfirstlane(ovfcnt[0]);
    if (novf > 0) {
        if (novf > OVF_MAX) novf = OVF_MAX;
        for (int j = 0; j < novf; ++j) {
            int4 e = ovf[j];
            if (e.x == n) {
                float w = __int_as_float(e.z);
                uint2 x = *(const uint2*)((const char*)hw2p +
                                          (((uint)e.y << 7) + lb8));
                ax = fmaf(w, __uint_as_float(x.x << 16), ax);
                ay = fmaf(w, __uint_as_float(x.x & 0xFFFF0000u), ay);
                az = fmaf(w, __uint_as_float(x.y << 16), az);
                aw = fmaf(w, __uint_as_float(x.y & 0xFFFF0000u), aw);
            }
        }
    }
    // --- bias + LN + ReLU (quad layout) + residual + bf16 pack ---
    int q = lane & 15;
    float di = dinv[n];
    float4 bb = ((const float4*)b)[q];
    float v0 = fmaf(ax, di, bb.x);
    float v1 = fmaf(ay, di, bb.y);
    float v2 = fmaf(az, di, bb.z);
    float v3 = fmaf(aw, di, bb.w);
    float m = quad_reduce_add((v0 + v1) + (v2 + v3)) * (1.0f / 64.0f);
    float d0 = v0 - m, d1 = v1 - m, d2 = v2 - m, d3 = v3 - m;
    float var = quad_reduce_add((d0 * d0 + d1 * d1) + (d2 * d2 + d3 * d3))
                * (1.0f / 64.0f);
    float rs = rsqrtf(var + 1e-5f);
    float4 gg = ((const float4*)g)[q];
    float4 ee = ((const float4*)be)[q];
    float y0 = fmaxf(fmaf(d0 * rs, gg.x, ee.x), 0.0f);
    float y1 = fmaxf(fmaf(d1 * rs, gg.y, ee.y), 0.0f);
    float y2 = fmaxf(fmaf(d2 * rs, gg.z, ee.z), 0.0f);
    float y3 = fmaxf(fmaf(d3 * rs, gg.w, ee.w), 0.0f);
    const float* R = (n < NU) ? (U + (size_t)n * D) : (I + (size_t)(n - NU) * D);
    float4 rr = ((const float4*)R)[q];
    if (lane < 16) {
        uint lo = (uint)f2bf(y0 + rr.x) | ((uint)f2bf(y1 + rr.y) << 16);
        uint hi = (uint)f2bf(y2 + rr.z) | ((uint)f2bf(y3 + rr.w) << 16);
        ((uint2*)out1)[(size_t)n * 16 + q] = make_uint2(lo, hi);
    }
}

// --- dual-node PAIR conv accumulate for k_conv2score (unchanged from R5) -----
#define CB_DECL(p, c) uint p##x##c##0, p##x##c##1, p##x##c##2, p##x##c##3, \
                           p##w##c##0, p##w##c##1, p##w##c##2, p##w##c##3;
#define CB_GET(p, c, i, P, rvv) { \
    uint r = (uint)__builtin_amdgcn_ds_bpermute(vodd4 + 8 * (P), (int)(rvv)); \
    p##w##c##i = r & 0xFFFC0000u; \
    p##x##c##i = *(const uint*)((const char*)hw2p + \
                                (((r & 0x3FFFFu) << 7) + lb4)); }
#define CB_ISSUE(p, c, P0, rvv) { CB_GET(p,c,0,(P0)+0,rvv) CB_GET(p,c,1,(P0)+1,rvv) \
                                  CB_GET(p,c,2,(P0)+2,rvv) CB_GET(p,c,3,(P0)+3,rvv) }
#define CB_FMA1(p, c, i, axv, ayv) { \
    axv = fmaf(__uint_as_float(p##w##c##i), \
               __uint_as_float(p##x##c##i << 16), axv); \
    ayv = fmaf(__uint_as_float(p##w##c##i), \
               __uint_as_float(p##x##c##i & 0xFFFF0000u), ayv); }
#define CB_FMA(p, c, axv, ayv) { CB_FMA1(p,c,0,axv,ayv) CB_FMA1(p,c,1,axv,ayv) \
                                 CB_FMA1(p,c,2,axv,ayv) CB_FMA1(p,c,3,axv,ayv) }

__device__ __forceinline__ void conv_accum2_dual(int nu, int ni, int lane,
        const uint* __restrict__ hw2p, const int* __restrict__ cursor,
        const uint* __restrict__ recs, const int4* __restrict__ ovf,
        const int* __restrict__ ovfcnt, float2* outu, float2* outi) {
    int cu = __builtin_amdgcn_readfirstlane(cursor[nu]); if (cu > CAP) cu = CAP;
    int ci = __builtin_amdgcn_readfirstlane(cursor[ni]); if (ci > CAP) ci = CAP;
    uint rvu = (lane < cu) ? recs[(size_t)nu * CAP + lane] : 0u;
    uint rvi = (lane < ci) ? recs[(size_t)ni * CAP + lane] : 0u;
    const int  vodd4 = (lane >> 5) << 2;
    const uint lb4   = (uint)(lane & 31) << 2;
    uint xsu = *(const uint*)((const char*)hw2p + (((uint)nu << 7) + lb4));
    uint xsi = *(const uint*)((const char*)hw2p + (((uint)ni << 7) + lb4));
    float uax = 0.f, uay = 0.f, iax = 0.f, iay = 0.f;
    int cpu_ = (cu + 7) & ~7, cpi_ = (ci + 7) & ~7;
    CB_DECL(u, A) CB_DECL(u, B) CB_DECL(u, G)
    CB_DECL(i, A) CB_DECL(i, B) CB_DECL(i, G)
    CB_ISSUE(u, A, 0, rvu) CB_ISSUE(i, A, 0, rvi)
    CB_ISSUE(u, B, 4, rvu) CB_ISSUE(i, B, 4, rvi)
    CB_ISSUE(u, G, 8, rvu) CB_ISSUE(i, G, 8, rvi)
    CB_FMA(u, A, uax, uay) CB_FMA(i, A, iax, iay)
    if (cpu_ > 24) CB_ISSUE(u, A, 12, rvu)
    if (cpi_ > 24) CB_ISSUE(i, A, 12, rvi)
    CB_FMA(u, B, uax, uay) CB_FMA(i, B, iax, iay)
    if (cpu_ > 32) CB_ISSUE(u, B, 16, rvu)
    if (cpi_ > 32) CB_ISSUE(i, B, 16, rvi)
    CB_FMA(u, G, uax, uay) CB_FMA(i, G, iax, iay)
    if (cpu_ > 40) CB_ISSUE(u, G, 20, rvu)
    if (cpi_ > 40) CB_ISSUE(i, G, 20, rvi)
    if (cpu_ > 24) CB_FMA(u, A, uax, uay)
    if (cpi_ > 24) CB_FMA(i, A, iax, iay)
    if (cpu_ > 32) CB_FMA(u, B, uax, uay)
    if (cpi_ > 32) CB_FMA(i, B, iax, iay)
    if (cpu_ > 40) CB_FMA(u, G, uax, uay)
    if (cpi_ > 40) CB_FMA(i, G, iax, iay)
    uax += __shfl_xor(uax, 32, 64); uay += __shfl_xor(uay, 32, 64);
    iax += __shfl_xor(iax, 32, 64); iay += __shfl_xor(iay, 32, 64);
    uax += __uint_as_float(xsu << 16); uay += __uint_as_float(xsu & 0xFFFF0000u);
    iax += __uint_as_float(xsi << 16); iay += __uint_as_float(xsi & 0xFFFF0000u);
    int novf = __builtin_amdgcn_readfirstlane(ovfcnt[0]);
    if (novf > 0) {
        if (novf > OVF_MAX) novf = OVF_MAX;
        for (int j = 0; j < novf; ++j) {
            int4 e = ovf[j];
            if (e.x == nu || e.x == ni) {
                float w = __int_as_float(e.z);
                uint x = hw2p[(size_t)e.y * 32 + (lane & 31)];
                float fx = __uint_as_float(x << 16);
                float fy = __uint_as_float(x & 0xFFFF0000u);
                if (e.x == nu) { uax = fmaf(w, fx, uax); uay = fmaf(w, fy, uay); }
                else           { iax = fmaf(w, fx, iax); iay = fmaf(w, fy, iay); }
            }
        }
    }
    *outu = make_float2(uax, uay);
    *outi = make_float2(iax, iay);
}

// bias + LN + ReLU on pair layout; returns (y0,y1) for feats (2p, 2p+1)
__device__ __forceinline__ float2 ln_relu2(float2 a, float di, int p,
        const float* __restrict__ b, const float* __restrict__ g,
        const float* __restrict__ be) {
    float2 bb = ((const float2*)b)[p];
    float v0 = fmaf(a.x, di, bb.x);
    float v1 = fmaf(a.y, di, bb.y);
    float m = half_reduce_add(v0 + v1) * (1.0f / 64.0f);
    float d0 = v0 - m, d1 = v1 - m;
    float var = half_reduce_add(d0 * d0 + d1 * d1) * (1.0f / 64.0f);
    float rs = rsqrtf(var + 1e-5f);
    float2 gg = ((const float2*)g)[p];
    float2 ee = ((const float2*)be)[p];
    return make_float2(fmaxf(fmaf(d0 * rs, gg.x, ee.x), 0.0f),
                       fmaxf(fmaf(d1 * rs, gg.y, ee.y), 0.0f));
}

// ------- layer-2 GEMM: hw2b = bf16((h1 @ W1) * dinv), h1 read as bf16 --------
__global__ __launch_bounds__(256) void k_gemm2(
        const ushort* __restrict__ hb, const float* __restrict__ W,
        const float* __restrict__ dinv, ushort* __restrict__ out) {
    int lane = threadIdx.x & 63;
    float wreg[64];                         // column `lane` of W1
    #pragma unroll
    for (int k = 0; k < 64; ++k) wreg[k] = W[k * 64 + lane];
    int wpb = blockDim.x >> 6;
    int wid = blockIdx.x * wpb + (threadIdx.x >> 6);
    int tw = gridDim.x * wpb;
    for (int n = wid; n < NN; n += tw) {
        float xv = __uint_as_float((uint)hb[(size_t)n * D + lane] << 16);
        float a0 = 0.f, a1 = 0.f, a2 = 0.f, a3 = 0.f;
        #pragma unroll
        for (int k = 0; k < 64; k += 4) {
            a0 = fmaf(lane_bcast(xv, k + 0), wreg[k + 0], a0);
            a1 = fmaf(lane_bcast(xv, k + 1), wreg[k + 1], a1);
            a2 = fmaf(lane_bcast(xv, k + 2), wreg[k + 2], a2);
            a3 = fmaf(lane_bcast(xv, k + 3), wreg[k + 3], a3);
        }
        out[(size_t)n * D + lane] = f2bf(((a0 + a1) + (a2 + a3)) * dinv[n]);
    }
}

// ------- FUSED layer-2 conv (sampled) + projection + scoring ------------------
// Wp lives in LDS; user & item convs run as one interleaved dual pipeline.
__global__ __launch_bounds__(256) void k_conv2score(
        const uint* __restrict__ hw2p, const int* __restrict__ cursor,
        const uint* __restrict__ recs, const int4* __restrict__ ovf,
        const int* __restrict__ ovfcnt, const float* __restrict__ dinv,
        const float* __restrict__ b, const float* __restrict__ g,
        const float* __restrict__ be, const int* __restrict__ users,
        const int* __restrict__ items, const uint* __restrict__ h1b,
        const float* __restrict__ Wp, const float* __restrict__ bp,
        const float* __restrict__ bu, const float* __restrict__ bi,
        const float* __restrict__ mu, float* __restrict__ out, int B) {
    __shared__ float wlds[64 * 64];        // Wp, 16 KB
    int t = threadIdx.x;
    for (int i = t; i < 64 * 64; i += 256) wlds[i] = Wp[i];
    __syncthreads();
    int lane = t & 63;
    float bpl = bp[lane];
    int q = lane & 31;
    int wpb = blockDim.x >> 6;
    int wid = blockIdx.x * wpb + (t >> 6);
    int tw = gridDim.x * wpb;
    for (int p = wid; p < B; p += tw) {
        int un = users[p];
        int in_ = NU + items[p];
        int nu = __builtin_amdgcn_readfirstlane(un);
        int ni = __builtin_amdgcn_readfirstlane(in_);
        float2 au, ai;
        conv_accum2_dual(nu, ni, lane, hw2p, cursor, recs, ovf, ovfcnt,
                         &au, &ai);
        float2 yu = ln_relu2(au, dinv[nu], q, b, g, be);
        float2 yi = ln_relu2(ai, dinv[ni], q, b, g, be);
        uint xu = h1b[(size_t)nu * 32 + q];
        uint xi = h1b[(size_t)ni * 32 + q];
        float2 hu = make_float2(yu.x + __uint_as_float(xu << 16),
                                yu.y + __uint_as_float(xu & 0xFFFF0000u));
        float2 hi = make_float2(yi.x + __uint_as_float(xi << 16),
                                yi.y + __uint_as_float(xi & 0xFFFF0000u));
        // --- projection (feat 2j from .x, 2j+1 from .y) + dot
        float pu = bpl, pi = bpl;
        #pragma unroll
        for (int j = 0; j < 32; ++j) {
            float w0 = wlds[(2 * j) * 64 + lane];
            float w1 = wlds[(2 * j + 1) * 64 + lane];
            pu = fmaf(lane_bcast(hu.x, j), w0, pu);
            pu = fmaf(lane_bcast(hu.y, j), w1, pu);
            pi = fmaf(lane_bcast(hi.x, j), w0, pi);
            pi = fmaf(lane_bcast(hi.y, j), w1, pi);
        }
        float dot = pu * pi;
        #pragma unroll
        for (int m = 32; m >= 1; m >>= 1) dot += __shfl_xor(dot, m, 64);
        if (lane == 0) {
            dot += bu[un] + bi[in_ - NU] + mu[0];
            out[p] = fminf(fmaxf(dot, 1.0f), 5.0f);
        }
    }
}

extern "C" void kernel_launch(void* const* d_in, const int* in_sizes, int n_in,
                              void* d_out, int out_size, void* d_ws, size_t ws_size,
                              hipStream_t stream) {
    const int*   users = (const int*)d_in[0];
    const int*   items = (const int*)d_in[1];
    const int*   ei2   = (const int*)d_in[2];
    const float* ew    = (const float*)d_in[3];
    const float* U     = (const float*)d_in[4];
    const float* I     = (const float*)d_in[5];
    const float* W0    = (const float*)d_in[6];
    const float* b0    = (const float*)d_in[7];
    const float* g0    = (const float*)d_in[8];
    const float* be0   = (const float*)d_in[9];
    const float* W1    = (const float*)d_in[10];
    const float* b1    = (const float*)d_in[11];
    const float* g1    = (const float*)d_in[12];
    const float* be1   = (const float*)d_in[13];
    const float* Wp    = (const float*)d_in[14];
    const float* bp    = (const float*)d_in[15];
    const float* bu    = (const float*)d_in[16];
    const float* bi    = (const float*)d_in[17];
    const float* mu    = (const float*)d_in[18];

    int B = in_sizes[0];
    int E = in_sizes[2] / 2;
    const int* srcp = ei2;
    const int* dstp = ei2 + E;

    // workspace carve-up (256B aligned)
    char* p = (char*)d_ws;
    auto alloc = [&](size_t bytes) -> char* {
        char* r = p;
        p += (bytes + 255) & ~(size_t)255;
        return r;
    };
    int*    cbuf    = (int*)  alloc((size_t)(NBINS * BCPAD + 32) * 4);  // padded bincur|spillcnt|ovfcnt
    int*    bincur  = cbuf;                       // stride BCPAD per bin
    int*    spillcnt= cbuf + NBINS * BCPAD;
    int*    ovfcnt  = cbuf + NBINS * BCPAD + 16;  // own cacheline
    int*    cursor  = (int*)  alloc((size_t)NN * 4);
    float*  dinv    = (float*)alloc((size_t)NN * 4);
    int4*   ovf     = (int4*) alloc((size_t)OVF_MAX * 16);
    uint2*  spill   = (uint2*)alloc((size_t)SPILL_CAP * 8);      // 2.1 MB
    uchar*  cnt8    = (uchar*)alloc((size_t)BIN_BLOCKS * NBINS); // 0.45 MB
    uint2*  binbuf  = (uint2*)alloc((size_t)NBINS * BINCAP * 8); // 27.4 MB
    uint*   recs    = (uint*) alloc((size_t)NN * CAP * 4);       // 28.2 MB
    ushort* hw2b    = (ushort*)alloc((size_t)NN * D * 2);        // 19.2 MB
    uint*   h1b     = (uint*) alloc((size_t)NN * 32 * 4);        // 19.2 MB (bf16)
    const uint* hw2p = (const uint*)hw2b;
    // tail ALIASES [hw2b, h1b] (38.4 MB >= 28.8 MB needed): tail is written by
    // k_bin and dead after k_regroup; hw2b is first written by k_gemm1 (after
    // regroup) and h1b by k_conv1. Lifetimes are disjoint.
    uint2*  tail    = (uint2*)hw2b;   // BIN_BLOCKS*NBINS*8 records = 28.8 MB

    hipMemsetAsync(cbuf, 0, (size_t)(NBINS * BCPAD + 32) * 4, stream);

    int gW = (NN + 3) / 4;          // one wave per node, 4 waves/block

    // CSR build: bin -> regroup(+tails+spill+deg+dinv)
    k_bin<<<BIN_BLOCKS, 256, 0, stream>>>(srcp, dstp, ew, bincur, binbuf,
                                          spill, spillcnt, tail, cnt8, E);
    k_regroup<<<NBINS, 256, 0, stream>>>(bincur, binbuf, spill, spillcnt,
                                         tail, cnt8, recs, cursor, dinv,
                                         ovf, ovfcnt);

    // layer 1 (all nodes)
    k_gemm1<<<2048, 256, 0, stream>>>(U, I, W0, dinv, hw2b);
    k_conv1<<<gW, 256, 0, stream>>>(hw2p, cursor, recs, ovf, ovfcnt, dinv,
                                    b0, g0, be0, U, I, h1b);
    // layer 2: gemm all nodes (bf16 in), then fused sampled conv+proj+score
    k_gemm2<<<2048, 256, 0, stream>>>((const ushort*)h1b, W1, dinv, hw2b);
    k_conv2score<<<2048, 256, 0, stream>>>(hw2p, cursor, recs, ovf, ovfcnt, dinv,
                                           b1, g1, be1, users, items, h1b,
                                           Wp, bp, bu, bi, mu,
                                           (float*)d_out, B);
}